// Round 15
// baseline (317.167 us; speedup 1.0000x reference)
//
#include <hip/hip_runtime.h>
#include <hip/hip_bf16.h>

#define C 256
#define HID 128
#define Bb_ 2
#define Hh 64
#define Ww 64
#define Nn_ 4096
#define NP 16
#define NC 16
#define KVSPLIT 8
#define KVB 32

typedef __bf16 bf16x8 __attribute__((ext_vector_type(8)));
typedef float f32x4 __attribute__((ext_vector_type(4)));

// ---------------------------------------------------------------------------
// Coalesced tiled LayerNorm -> x1T, x2T bf16 [B][N][C]; also emits qryT bf16.
__global__ __launch_bounds__(256) void lnT_kernel(
    const float* __restrict__ x,
    const float* __restrict__ g1, const float* __restrict__ b1,
    const float* __restrict__ g2, const float* __restrict__ b2,
    __hip_bfloat16* __restrict__ x1T, __hip_bfloat16* __restrict__ x2T,
    __hip_bfloat16* __restrict__ qryTb)
{
    int blk = blockIdx.x;
    int b = blk >> 6;
    int n0 = (blk & 63) << 6;
    int t = threadIdx.x;
    __shared__ __hip_bfloat16 xs[64][258];
    __shared__ float rs4[4][64], rq4[4][64], mean[64], inv[64];
    int j = t & 63, cg = t >> 6;
    float s = 0.f, q = 0.f;
    for (int it = 0; it < 64; ++it) {
        int c = it * 4 + cg;
        float v = x[((long)b * C + c) * Nn_ + n0 + j];
        xs[j][c] = __float2bfloat16(v);
        s += v; q += v * v;
    }
    rs4[cg][j] = s; rq4[cg][j] = q;
    __syncthreads();
    if (t < 64) {
        float S = rs4[0][t] + rs4[1][t] + rs4[2][t] + rs4[3][t];
        float Q = rq4[0][t] + rq4[1][t] + rq4[2][t] + rq4[3][t];
        float m = S * (1.0f / C);
        float var = Q * (1.0f / C) - m * m;
        mean[t] = m; inv[t] = rsqrtf(var + 1e-5f);
    }
    __syncthreads();
    float G1 = g1[t], B1 = b1[t], G2 = g2[t], B2 = b2[t];
    for (int j2 = 0; j2 < 64; ++j2) {
        float v = __bfloat162float(xs[j2][t]);
        float xn = (v - mean[j2]) * inv[j2];
        long o = ((long)b * Nn_ + n0 + j2) * C + t;
        x1T[o] = __float2bfloat16(xn * G1 + B1);
        x2T[o] = __float2bfloat16(xn * G2 + B2);
        qryTb[o] = xs[j2][t];
    }
}

// ---------------------------------------------------------------------------
__global__ __launch_bounds__(256) void gate_kernel(
    const float* __restrict__ arch, const float* __restrict__ Wg,
    const float* __restrict__ bg, float* __restrict__ gate)
{
    int b = blockIdx.x;
    int o = threadIdx.x;
    __shared__ float guide[C];
    float s = 0.f;
    for (int p = 0; p < NP; ++p) s += arch[(long)b * NP * C + (long)p * C + o];
    guide[o] = s * (1.0f / NP);
    __syncthreads();
    float acc = bg[o];
    for (int cc = 0; cc < C; ++cc) acc += guide[cc] * Wg[(long)o * C + cc];
    gate[b * C + o] = 1.0f / (1.0f + __expf(-acc));
}

// ---------------------------------------------------------------------------
#define QSCALE 0.09016844005429271f   // log2(e)/16
__global__ __launch_bounds__(256) void build_wqkv(
    const float* __restrict__ Wqkv, const float* __restrict__ bqkv,
    const float* __restrict__ gate,
    __hip_bfloat16* __restrict__ WqkvG, float* __restrict__ biasCol)
{
    long i = (long)blockIdx.x * 256 + threadIdx.x;
    long total = (long)Bb_ * 3 * C * C;
    if (i < total) {
        long b = i / (3 * C * C);
        long rem = i % (3 * C * C);
        int o = (int)(rem / C);
        float v = Wqkv[rem];
        if (o < C) v *= QSCALE;
        else if (o < 2 * C) v *= gate[b * C + (o - C)];
        WqkvG[i] = __float2bfloat16(v);
    }
    if (i < (long)Bb_ * 3 * C) {
        long b = i / (3 * C);
        int o = (int)(i % (3 * C));
        float v = bqkv[o];
        if (o < C) v *= QSCALE;
        else if (o < 2 * C) v *= gate[b * C + (o - C)];
        biasCol[i] = v;
    }
}

// ---------------------------------------------------------------------------
// Cast Wproj, Wf2 to bf16 and build Wtap [9][O][512] from Wf1.
__global__ __launch_bounds__(256) void cast_all(
    const float* __restrict__ Wproj, const float* __restrict__ Wf2,
    const float* __restrict__ Wf1,
    __hip_bfloat16* __restrict__ Wprojb, __hip_bfloat16* __restrict__ Wf2b,
    __hip_bfloat16* __restrict__ Wtap)
{
    long i = (long)blockIdx.x * 256 + threadIdx.x;
    const long nP = (long)C * C;
    const long nT = 9l * C * 2 * C;
    if (i < nP) { Wprojb[i] = __float2bfloat16(Wproj[i]); return; }
    i -= nP;
    if (i < nP) { Wf2b[i] = __float2bfloat16(Wf2[i]); return; }
    i -= nP;
    if (i < nT) {
        int tap = (int)(i / (C * 2 * C));
        long rem = i % (C * 2 * C);
        int o = (int)(rem / (2 * C)), ic = (int)(rem % (2 * C));
        Wtap[i] = __float2bfloat16(Wf1[((long)o * 2 * C + ic) * 9 + tap]);
    }
}

// ---------------------------------------------------------------------------
// Cross-attention algebraic prep (fold Wq/Wout through the 16-token attn).
__global__ __launch_bounds__(256) void cross_prep(
    const float* __restrict__ ctx, const float* __restrict__ Wkv,
    const float* __restrict__ bkv, const float* __restrict__ Wq,
    const float* __restrict__ bq, const float* __restrict__ Wout,
    float* __restrict__ ktil, float* __restrict__ beta,
    float* __restrict__ vtil)
{
    int b = blockIdx.x >> 4, m = blockIdx.x & 15;
    int t = threadIdx.x;
    __shared__ float cs[C], kl[C], red[128];
    cs[t] = ctx[((long)b * NC + m) * C + t];
    __syncthreads();
    float acc = bkv[t];
    for (int c = 0; c < C; ++c) acc += cs[c] * Wkv[(long)t * C + c];
    kl[t] = acc;
    __syncthreads();
    const float scc = 0.08838834764831845f;
    float kt = 0.f;
    for (int h = 0; h < HID; ++h) kt += kl[h] * Wq[(long)h * C + t];
    ktil[((long)b * NC + m) * C + t] = kt * scc;
    float vt = 0.f;
    for (int h = 0; h < HID; ++h) vt += kl[HID + h] * Wout[(long)t * HID + h];
    vtil[((long)b * C + t) * NC + m] = vt;
    if (t < 128) red[t] = bq[t] * kl[t];
    __syncthreads();
    for (int s = 64; s > 0; s >>= 1) {
        if (t < s) red[t] += red[t + s];
        __syncthreads();
    }
    if (t == 0) beta[b * NC + m] = red[0] * scc;
}

// ---------------------------------------------------------------------------
// Fused cross attention -> catT right half (qryT bf16)
__global__ __launch_bounds__(256) void cross_fused(
    const __hip_bfloat16* __restrict__ x2T, const __hip_bfloat16* __restrict__ qryTb,
    const float* __restrict__ ktil, const float* __restrict__ beta,
    const float* __restrict__ vtil, const float* __restrict__ bout,
    __hip_bfloat16* __restrict__ catT)
{
    int blk = blockIdx.x;
    int b = blk >> 6;
    long n = (long)(blk & 63) * 64 + (threadIdx.x >> 2);
    int cg = threadIdx.x & 3;
    int t = threadIdx.x;
    __shared__ float kt[NC * C];
    __shared__ float vt[C * NC];
    for (int r = 0; r < 16; ++r) {
        int idx = r * 256 + t;
        int m = idx >> 8, c = idx & 255;
        kt[m * 256 + (c & 63) * 4 + (c >> 6)] = ktil[((long)b * NC + m) * C + c];
        int c2 = idx >> 4, m2 = idx & 15;
        vt[((c2 & 63) * 4 + (c2 >> 6)) * 16 + m2] = vtil[((long)b * C + c2) * NC + m2];
    }
    __syncthreads();

    float s[NC];
    #pragma unroll
    for (int m = 0; m < NC; ++m) s[m] = 0.f;
    const __hip_bfloat16* xr = x2T + ((long)b * Nn_ + n) * C + cg * 64;
    for (int c8 = 0; c8 < 8; ++c8) {
        bf16x8 xv = *(const bf16x8*)(xr + c8 * 8);
        #pragma unroll
        for (int e = 0; e < 8; ++e) {
            float xf = (float)xv[e];
            int ic = c8 * 8 + e;
            #pragma unroll
            for (int m = 0; m < NC; ++m)
                s[m] += xf * kt[m * 256 + ic * 4 + cg];
        }
    }
    #pragma unroll
    for (int m = 0; m < NC; ++m) {
        s[m] += __shfl_xor(s[m], 1);
        s[m] += __shfl_xor(s[m], 2);
        s[m] += beta[b * NC + m];
    }
    float mx = -1e30f;
    #pragma unroll
    for (int m = 0; m < NC; ++m) mx = fmaxf(mx, s[m]);
    float sum = 0.f;
    #pragma unroll
    for (int m = 0; m < NC; ++m) { s[m] = __expf(s[m] - mx); sum += s[m]; }
    float dn = 1.0f / sum;

    const __hip_bfloat16* qr = qryTb + ((long)b * Nn_ + n) * C + cg * 64;
    __hip_bfloat16* outp = catT + ((long)b * Nn_ + n) * (2 * C) + C + cg * 64;
    for (int c8 = 0; c8 < 8; ++c8) {
        union { ushort4 u; __hip_bfloat16 h[4]; } cv0, cv1;
        #pragma unroll
        for (int e = 0; e < 8; ++e) {
            int ic = c8 * 8 + e;
            int c = cg * 64 + ic;
            float acc = __bfloat162float(qr[ic]) + bout[c];
            float pv = 0.f;
            #pragma unroll
            for (int m = 0; m < NC; ++m)
                pv += vt[(ic * 4 + cg) * 16 + m] * s[m];
            acc += pv * dn;
            if (e < 4) cv0.h[e] = __float2bfloat16(acc);
            else       cv1.h[e - 4] = __float2bfloat16(acc);
        }
        *(ushort4*)(outp + c8 * 8) = cv0.u;
        *(ushort4*)(outp + c8 * 8 + 4) = cv1.u;
    }
}

// ---------------------------------------------------------------------------
// MFMA bf16 GEMM; resid may be fp32 or bf16.
__global__ __launch_bounds__(256) void gemm_bt(
    const __hip_bfloat16* __restrict__ A,
    const __hip_bfloat16* __restrict__ Bt,
    float* __restrict__ D,
    __hip_bfloat16* __restrict__ Dbf,
    int M, int N, int K, int lda, int ldb, int ldd,
    long batchA, long batchB, long batchD,
    const float* __restrict__ biasRow,
    const float* __restrict__ biasCol, long bcStride,
    const float* __restrict__ resid,
    const __hip_bfloat16* __restrict__ residB, int ldr, long batchR,
    float alpha, int relu)
{
    __shared__ __align__(16) __hip_bfloat16 As[128 * 32];
    __shared__ __align__(16) __hip_bfloat16 Bs[128 * 32];
    int bz = blockIdx.z;
    const __hip_bfloat16* Ab = A + (long)bz * batchA;
    const __hip_bfloat16* Bb = Bt + (long)bz * batchB;
    int m0 = blockIdx.y * 128, n0 = blockIdx.x * 128;
    int tid = threadIdx.x;
    int lane = tid & 63, wave = tid >> 6;
    int wr = wave >> 1, wc = wave & 1;
    int lr = lane & 15, lg = lane >> 4;

    f32x4 acc[4][4];
    #pragma unroll
    for (int i = 0; i < 4; ++i)
        #pragma unroll
        for (int j = 0; j < 4; ++j)
            #pragma unroll
            for (int r = 0; r < 4; ++r) acc[i][j][r] = 0.f;

    for (int k0 = 0; k0 < K; k0 += 32) {
        #pragma unroll
        for (int q = 0; q < 2; ++q) {
            int idx = q * 256 + tid;
            int row = idx >> 2;
            int ke = (idx & 3) * 8;
            uint4 va = *(const uint4*)(Ab + (long)(m0 + row) * lda + k0 + ke);
            uint4 vb = *(const uint4*)(Bb + (long)(n0 + row) * ldb + k0 + ke);
            ((uint4*)As)[idx] = va;
            ((uint4*)Bs)[idx] = vb;
        }
        __syncthreads();
        bf16x8 af[4], bfr[4];
        #pragma unroll
        for (int i = 0; i < 4; ++i)
            af[i] = *(const bf16x8*)(As + (wr * 64 + i * 16 + lr) * 32 + lg * 8);
        #pragma unroll
        for (int j = 0; j < 4; ++j)
            bfr[j] = *(const bf16x8*)(Bs + (wc * 64 + j * 16 + lr) * 32 + lg * 8);
        #pragma unroll
        for (int i = 0; i < 4; ++i)
            #pragma unroll
            for (int j = 0; j < 4; ++j)
                acc[i][j] = __builtin_amdgcn_mfma_f32_16x16x32_bf16(af[i], bfr[j], acc[i][j], 0, 0, 0);
        __syncthreads();
    }

    int colc = n0 + wc * 64 + lr;
    #pragma unroll
    for (int i = 0; i < 4; ++i) {
        #pragma unroll
        for (int r = 0; r < 4; ++r) {
            int row = m0 + wr * 64 + i * 16 + lg * 4 + r;
            float brv = biasRow ? biasRow[row] : 0.f;
            #pragma unroll
            for (int j = 0; j < 4; ++j) {
                int cc = colc + j * 16;
                float v = acc[i][j][r] * alpha + brv;
                if (biasCol) v += biasCol[bz * bcStride + cc];
                if (resid) v += resid[(long)bz * batchR + (long)row * ldr + cc];
                if (residB) v += __bfloat162float(residB[(long)bz * batchR + (long)row * ldr + cc]);
                if (relu) v = fmaxf(v, 0.f);
                long oa = (long)bz * batchD + (long)row * ldd + cc;
                if (Dbf) Dbf[oa] = __float2bfloat16(v);
                else     D[oa] = v;
            }
        }
    }
}

// ---------------------------------------------------------------------------
__global__ __launch_bounds__(256) void extract_v(
    const __hip_bfloat16* __restrict__ qkvT, __hip_bfloat16* __restrict__ vB)
{
    int b = blockIdx.z;
    int c0 = blockIdx.y * 64, m0 = blockIdx.x * 64;
    __shared__ __hip_bfloat16 tb[64][66];
    int tx = threadIdx.x & 63, tg = threadIdx.x >> 6;
    for (int rr = tg; rr < 64; rr += 4)
        tb[rr][tx] = qkvT[((long)b * Nn_ + m0 + rr) * (3 * C) + 2 * C + c0 + tx];
    __syncthreads();
    for (int rr = tg; rr < 64; rr += 4)
        vB[((long)b * C + c0 + rr) * Nn_ + m0 + tx] = tb[tx][rr];
}

// ---------------------------------------------------------------------------
// Flash attention v6: 32 q-rows per wave (B-operand reuse across 2 q-subtiles
// halves LDS reads per MFMA; staging & barriers per q-row halve).
// Block = 128 q-rows, grid (32, KVSPLIT=8, B) = 512 blocks (2/CU, LDS 40KB).
__global__ __launch_bounds__(256) void flash_attn(
    const __hip_bfloat16* __restrict__ qkvT,
    const __hip_bfloat16* __restrict__ vB,
    __hip_bfloat16* __restrict__ Opart,   // [B][KVSPLIT][N][256] bf16
    float* __restrict__ lsum)             // [B][KVSPLIT][N]
{
    int qb = blockIdx.x, sp = blockIdx.y, b = blockIdx.z;
    int n0 = qb * 128;
    int tid = threadIdx.x;
    int lane = tid & 63, w = tid >> 6;
    int lr = lane & 15, lg = lane >> 4;

    __shared__ __align__(16) char Ks[32 * 512];    // 16KB
    __shared__ __align__(16) char Vs[128 * 128];   // 16KB (d-pairs interleaved)
    __shared__ __align__(16) char Pl[64 * 128];    // 8KB (128 q-rows pair-packed)

    // Q fragments for 2 q-subtiles (rows w*32 + qi*16 + lr)
    bf16x8 qf[2][8];
    #pragma unroll
    for (int qi = 0; qi < 2; ++qi) {
        const __hip_bfloat16* qp =
            qkvT + ((long)b * Nn_ + n0 + w * 32 + qi * 16 + lr) * (3 * C);
        #pragma unroll
        for (int ks = 0; ks < 8; ++ks)
            qf[qi][ks] = *(const bf16x8*)(qp + ks * 32 + lg * 8);
    }

    const __hip_bfloat16* kbase = qkvT + ((long)b * Nn_) * (3 * C) + C;
    const __hip_bfloat16* vbase = vB + (long)b * C * Nn_;
    int kvBeg = sp * (Nn_ / KVSPLIT);

    int krow[4], kc[4], koff[4], vd[4], vc[4], voff[4];
    #pragma unroll
    for (int ps = 0; ps < 4; ++ps) {
        int id = ps * 256 + tid;
        krow[ps] = id >> 5; kc[ps] = id & 31;
        koff[ps] = krow[ps] * 512 + ((kc[ps] * 16) ^ ((krow[ps] & 7) << 4));
        vd[ps] = id >> 2; vc[ps] = id & 3;
        int vp = vd[ps] >> 1;
        voff[ps] = vp * 128 + ((((vd[ps] & 1) * 64) + vc[ps] * 16) ^ ((vp & 7) << 4));
    }

    f32x4 Oacc[2][16];
    #pragma unroll
    for (int qi = 0; qi < 2; ++qi)
        #pragma unroll
        for (int jd = 0; jd < 16; ++jd)
            #pragma unroll
            for (int r = 0; r < 4; ++r) Oacc[qi][jd][r] = 0.f;
    float l_r[2][4] = {{0.f,0.f,0.f,0.f},{0.f,0.f,0.f,0.f}};

    const int NT = (Nn_ / KVSPLIT) / KVB;   // 16
    for (int t = 0; t < NT; ++t) {
        int kv0 = kvBeg + t * KVB;
        // ---- stage K+V (interleaved load/store to cap register liveness)
        #pragma unroll
        for (int ps = 0; ps < 4; ++ps) {
            uint4 krv = *(const uint4*)(kbase + (long)(kv0 + krow[ps]) * (3 * C) + kc[ps] * 8);
            *(uint4*)(Ks + koff[ps]) = krv;
            uint4 vrv = *(const uint4*)(vbase + (long)vd[ps] * Nn_ + kv0 + vc[ps] * 8);
            *(uint4*)(Vs + voff[ps]) = vrv;
        }
        __syncthreads();
        // ---- S = Q K^T (log2-domain); K frags reused across both q-subtiles
        f32x4 sacc[2][2];
        #pragma unroll
        for (int qi = 0; qi < 2; ++qi)
            #pragma unroll
            for (int j = 0; j < 2; ++j)
                #pragma unroll
                for (int r = 0; r < 4; ++r) sacc[qi][j][r] = 0.f;
        __builtin_amdgcn_s_setprio(1);
        #pragma unroll
        for (int ks = 0; ks < 8; ++ks) {
            #pragma unroll
            for (int j = 0; j < 2; ++j) {
                int row = j * 16 + lr;
                bf16x8 kf = *(const bf16x8*)(Ks + row * 512 +
                            ((ks * 64 + lg * 16) ^ ((row & 7) << 4)));
                sacc[0][j] = __builtin_amdgcn_mfma_f32_16x16x32_bf16(qf[0][ks], kf, sacc[0][j], 0, 0, 0);
                sacc[1][j] = __builtin_amdgcn_mfma_f32_16x16x32_bf16(qf[1][ks], kf, sacc[1][j], 0, 0, 0);
            }
        }
        __builtin_amdgcn_s_setprio(0);
        // ---- P = exp2(S) -> Pl
        #pragma unroll
        for (int qi = 0; qi < 2; ++qi)
            #pragma unroll
            for (int j = 0; j < 2; ++j)
                #pragma unroll
                for (int r = 0; r < 4; ++r) {
                    float p = __builtin_amdgcn_exp2f(sacc[qi][j][r]);
                    l_r[qi][r] += p;
                    int prow = w * 32 + qi * 16 + 4 * lg + r;
                    int pp = prow >> 1;
                    *(__hip_bfloat16*)(Pl + pp * 128 +
                        ((((prow & 1) * 64) + (j * 16 + lr) * 2) ^ ((pp & 7) << 4))) =
                        __float2bfloat16(p);
                }
        // ---- O += P V^T; V frags reused across both q-subtiles
        __builtin_amdgcn_s_setprio(1);
        {
            bf16x8 pf[2];
            #pragma unroll
            for (int qi = 0; qi < 2; ++qi) {
                int prow = w * 32 + qi * 16 + lr;
                int pp = prow >> 1;
                pf[qi] = *(const bf16x8*)(Pl + pp * 128 +
                         ((((prow & 1) * 64) + lg * 16) ^ ((pp & 7) << 4)));
            }
            #pragma unroll
            for (int jd = 0; jd < 16; ++jd) {
                int vrw = jd * 16 + lr;
                int vp = vrw >> 1;
                bf16x8 vf = *(const bf16x8*)(Vs + vp * 128 +
                            ((((vrw & 1) * 64) + lg * 16) ^ ((vp & 7) << 4)));
                Oacc[0][jd] = __builtin_amdgcn_mfma_f32_16x16x32_bf16(pf[0], vf, Oacc[0][jd], 0, 0, 0);
                Oacc[1][jd] = __builtin_amdgcn_mfma_f32_16x16x32_bf16(pf[1], vf, Oacc[1][jd], 0, 0, 0);
            }
        }
        __builtin_amdgcn_s_setprio(0);
        __syncthreads();
    }

    #pragma unroll
    for (int qi = 0; qi < 2; ++qi)
        #pragma unroll
        for (int r = 0; r < 4; ++r) {
            float v = l_r[qi][r];
            #pragma unroll
            for (int off = 1; off <= 8; off <<= 1)
                v += __shfl_xor(v, off);
            l_r[qi][r] = v;
        }

    __hip_bfloat16* Op = Opart + (((long)b * KVSPLIT + sp) * Nn_ + n0) * 256;
    #pragma unroll
    for (int qi = 0; qi < 2; ++qi)
        #pragma unroll
        for (int jd = 0; jd < 16; ++jd)
            #pragma unroll
            for (int r = 0; r < 4; ++r) {
                int row = w * 32 + qi * 16 + lg * 4 + r;
                Op[(long)row * 256 + jd * 16 + lr] = __float2bfloat16(Oacc[qi][jd][r]);
            }
    if (lr == 0) {
        float* lp = lsum + ((long)b * KVSPLIT + sp) * Nn_ + n0;
        #pragma unroll
        for (int qi = 0; qi < 2; ++qi)
            #pragma unroll
            for (int r = 0; r < 4; ++r)
                lp[w * 32 + qi * 16 + lg * 4 + r] = l_r[qi][r];
    }
}

// ---------------------------------------------------------------------------
__global__ __launch_bounds__(256) void merge_flash(
    const __hip_bfloat16* __restrict__ Opart, const float* __restrict__ lsum,
    __hip_bfloat16* __restrict__ refsT)
{
    long gi = (long)blockIdx.x * 256 + threadIdx.x;
    long row = gi >> 6;
    int c4 = (int)(gi & 63) * 4;
    long b = row / Nn_, n = row % Nn_;
    float l = 0.f;
    float o0 = 0.f, o1 = 0.f, o2 = 0.f, o3 = 0.f;
    #pragma unroll
    for (int sp = 0; sp < KVSPLIT; ++sp) {
        long rr = (b * KVSPLIT + sp) * Nn_ + n;
        l += lsum[rr];
        union { ushort4 u; __hip_bfloat16 h[4]; } rv;
        rv.u = *(const ushort4*)(Opart + rr * 256 + c4);
        o0 += __bfloat162float(rv.h[0]);
        o1 += __bfloat162float(rv.h[1]);
        o2 += __bfloat162float(rv.h[2]);
        o3 += __bfloat162float(rv.h[3]);
    }
    float dn = 1.0f / l;
    union { ushort4 u; __hip_bfloat16 h[4]; } cv;
    cv.h[0] = __float2bfloat16(o0 * dn);
    cv.h[1] = __float2bfloat16(o1 * dn);
    cv.h[2] = __float2bfloat16(o2 * dn);
    cv.h[3] = __float2bfloat16(o3 * dn);
    *(ushort4*)(refsT + (b * Nn_ + n) * 256 + c4) = cv.u;
}

// ---------------------------------------------------------------------------
// Implicit-GEMM 3x3 conv, 9-way tap-split (1152 blocks). partials bf16.
__global__ __launch_bounds__(256) void conv3x3_gemm(
    const __hip_bfloat16* __restrict__ catT,
    const __hip_bfloat16* __restrict__ Wtap,
    __hip_bfloat16* __restrict__ partials)
{
    __shared__ __align__(16) __hip_bfloat16 As[128 * 32];
    __shared__ __align__(16) __hip_bfloat16 Bs[128 * 32];
    int z = blockIdx.z;
    int b = z / 9, sp = z % 9;
    int dh = sp / 3 - 1, dw = sp % 3 - 1;
    int o0 = blockIdx.x * 128, m0 = blockIdx.y * 128;
    int tid = threadIdx.x;
    int lane = tid & 63, wave = tid >> 6;
    int wr = wave >> 1, wc = wave & 1;
    int lr = lane & 15, lg = lane >> 4;
    const __hip_bfloat16* cb = catT + (long)b * Nn_ * (2 * C);
    const __hip_bfloat16* wt = Wtap + (long)sp * C * (2 * C);

    f32x4 acc[4][4];
    #pragma unroll
    for (int i = 0; i < 4; ++i)
        #pragma unroll
        for (int j = 0; j < 4; ++j)
            #pragma unroll
            for (int r = 0; r < 4; ++r) acc[i][j][r] = 0.f;

    for (int k0 = 0; k0 < 2 * C; k0 += 32) {
        #pragma unroll
        for (int q = 0; q < 2; ++q) {
            int idx = q * 256 + tid;
            int row = idx >> 2;
            int ke = (idx & 3) * 8;
            int gm = m0 + row;
            int h = (gm >> 6) + dh, w2 = (gm & 63) + dw;
            uint4 va = {0, 0, 0, 0};
            if ((unsigned)h < 64u && (unsigned)w2 < 64u)
                va = *(const uint4*)(cb + ((long)((h << 6) + w2)) * (2 * C) + k0 + ke);
            ((uint4*)As)[idx] = va;
            ((uint4*)Bs)[idx] = *(const uint4*)(wt + (long)(o0 + row) * (2 * C) + k0 + ke);
        }
        __syncthreads();
        bf16x8 af[4], bfr[4];
        #pragma unroll
        for (int i = 0; i < 4; ++i)
            af[i] = *(const bf16x8*)(As + (wr * 64 + i * 16 + lr) * 32 + lg * 8);
        #pragma unroll
        for (int j = 0; j < 4; ++j)
            bfr[j] = *(const bf16x8*)(Bs + (wc * 64 + j * 16 + lr) * 32 + lg * 8);
        #pragma unroll
        for (int i = 0; i < 4; ++i)
            #pragma unroll
            for (int j = 0; j < 4; ++j)
                acc[i][j] = __builtin_amdgcn_mfma_f32_16x16x32_bf16(af[i], bfr[j], acc[i][j], 0, 0, 0);
        __syncthreads();
    }

    __hip_bfloat16* Dp = partials + ((long)(b * 9 + sp) * Nn_ + m0) * 256;
    #pragma unroll
    for (int i = 0; i < 4; ++i)
        #pragma unroll
        for (int r = 0; r < 4; ++r) {
            int row = wr * 64 + i * 16 + lg * 4 + r;
            #pragma unroll
            for (int j = 0; j < 4; ++j)
                Dp[(long)row * 256 + o0 + wc * 64 + j * 16 + lr] =
                    __float2bfloat16(acc[i][j][r]);
        }
}

// ---------------------------------------------------------------------------
__global__ __launch_bounds__(256) void reduce_partials(
    const __hip_bfloat16* __restrict__ part, long partStride,
    __hip_bfloat16* __restrict__ out, long n)
{
    long i = ((long)blockIdx.x * 256 + threadIdx.x) * 4;
    if (i >= n) return;
    float a[4] = {0.f, 0.f, 0.f, 0.f};
    #pragma unroll
    for (int sp = 0; sp < 9; ++sp) {
        union { ushort4 u; __hip_bfloat16 h[4]; } rv;
        rv.u = *(const ushort4*)(part + (long)sp * partStride + i);
        #pragma unroll
        for (int k = 0; k < 4; ++k) a[k] += __bfloat162float(rv.h[k]);
    }
    union { ushort4 u; __hip_bfloat16 h[4]; } cv;
    #pragma unroll
    for (int k = 0; k < 4; ++k)
        cv.h[k] = __float2bfloat16(fmaxf(a[k], 0.f));
    *(ushort4*)(out + i) = cv.u;
}

// ---------------------------------------------------------------------------
extern "C" void kernel_launch(void* const* d_in, const int* in_sizes, int n_in,
                              void* d_out, int out_size, void* d_ws, size_t ws_size,
                              hipStream_t stream)
{
    const float* qry   = (const float*)d_in[0];
    const float* arch  = (const float*)d_in[1];
    const float* ctx   = (const float*)d_in[2];
    const float* ln1_g = (const float*)d_in[3];
    const float* ln1_b = (const float*)d_in[4];
    const float* Wqkv  = (const float*)d_in[5];
    const float* bqkv  = (const float*)d_in[6];
    const float* Wproj = (const float*)d_in[7];
    const float* bproj = (const float*)d_in[8];
    const float* Wg    = (const float*)d_in[9];
    const float* bg    = (const float*)d_in[10];
    const float* ln2_g = (const float*)d_in[11];
    const float* ln2_b = (const float*)d_in[12];
    const float* Wq    = (const float*)d_in[13];
    const float* bq    = (const float*)d_in[14];
    const float* Wkv   = (const float*)d_in[15];
    const float* bkv   = (const float*)d_in[16];
    const float* Wout  = (const float*)d_in[17];
    const float* bout  = (const float*)d_in[18];
    const float* Wf1   = (const float*)d_in[19];
    const float* Wf2   = (const float*)d_in[20];
    const float* bf2   = (const float*)d_in[21];
    float* out = (float*)d_out;

    const long CN = (long)C * Nn_;
    const long MN = (long)Nn_ * C;
    char* ws = (char*)d_ws;
    size_t off = 0;
    auto alloc = [&](size_t bytes) -> char* {
        char* p = ws + off;
        off += (bytes + 255) & ~size_t(255);
        return p;
    };
    float* lbuf     = (float*)alloc((long)Bb_ * KVSPLIT * Nn_ * 4);
    float* gate     = (float*)alloc(Bb_ * C * 4);
    float* biasCol  = (float*)alloc((long)Bb_ * 3 * C * 4);
    float* ktil     = (float*)alloc((long)Bb_ * NC * C * 4);
    float* betab    = (float*)alloc((long)Bb_ * NC * 4);
    float* vtil     = (float*)alloc((long)Bb_ * C * NC * 4);
    __hip_bfloat16* Opart = (__hip_bfloat16*)alloc((long)Bb_ * KVSPLIT * MN * 2);
    __hip_bfloat16* convPart = (__hip_bfloat16*)alloc((long)Bb_ * 9 * MN * 2);
    __hip_bfloat16* qryTb = (__hip_bfloat16*)alloc(Bb_ * MN * 2);
    __hip_bfloat16* x1T   = (__hip_bfloat16*)alloc(Bb_ * MN * 2);
    __hip_bfloat16* x2T   = (__hip_bfloat16*)alloc(Bb_ * MN * 2);
    __hip_bfloat16* qkvT  = (__hip_bfloat16*)alloc((long)Bb_ * Nn_ * 3 * C * 2);
    __hip_bfloat16* vB    = (__hip_bfloat16*)alloc(Bb_ * CN * 2);
    __hip_bfloat16* refsT = (__hip_bfloat16*)alloc(Bb_ * MN * 2);
    __hip_bfloat16* catT  = (__hip_bfloat16*)alloc((long)Bb_ * Nn_ * 2 * C * 2);
    __hip_bfloat16* y1T   = (__hip_bfloat16*)alloc(Bb_ * MN * 2);
    __hip_bfloat16* WqkvG = (__hip_bfloat16*)alloc((long)Bb_ * 3 * C * C * 2);
    __hip_bfloat16* Wprojb= (__hip_bfloat16*)alloc((long)C * C * 2);
    __hip_bfloat16* Wf2b  = (__hip_bfloat16*)alloc((long)C * C * 2);
    __hip_bfloat16* Wtap  = (__hip_bfloat16*)alloc((long)9 * C * 2 * C * 2);

    // 1. layernorm (+ bf16 qry transpose fused)
    lnT_kernel<<<Bb_ * (Nn_ / 64), 256, 0, stream>>>(
        qry, ln1_g, ln1_b, ln2_g, ln2_b, x1T, x2T, qryTb);

    // 2. gate + weight prep + cross prep
    gate_kernel<<<Bb_, 256, 0, stream>>>(arch, Wg, bg, gate);
    build_wqkv<<<(Bb_ * 3 * C * C + 255) / 256, 256, 0, stream>>>(Wqkv, bqkv, gate, WqkvG, biasCol);
    {
        long total = (long)C * C * 2 + 9l * C * 2 * C;
        cast_all<<<(int)((total + 255) / 256), 256, 0, stream>>>(
            Wproj, Wf2, Wf1, Wprojb, Wf2b, Wtap);
    }
    cross_prep<<<Bb_ * NC, 256, 0, stream>>>(ctx, Wkv, bkv, Wq, bq, Wout, ktil, betab, vtil);

    // 3. qkvT = x1T @ WqkvG^T + biasCol  -> bf16 [B][N][768]
    gemm_bt<<<dim3(6, 32, Bb_), 256, 0, stream>>>(
        x1T, WqkvG, nullptr, qkvT, Nn_, 3 * C, C, C, C, 3 * C,
        MN, (long)3 * C * C, (long)Nn_ * 3 * C,
        nullptr, biasCol, 3 * C, nullptr, nullptr, 0, 0, 1.0f, 0);

    // 4. v -> vB [B][C][N]
    extract_v<<<dim3(Nn_ / 64, C / 64, Bb_), 256, 0, stream>>>(qkvT, vB);

    // 5. flash attention + merge -> refsT bf16 [B][N][C]
    flash_attn<<<dim3(Nn_ / 128, KVSPLIT, Bb_), 256, 0, stream>>>(qkvT, vB, Opart, lbuf);
    merge_flash<<<(int)((long)Bb_ * Nn_ * 64 / 256), 256, 0, stream>>>(Opart, lbuf, refsT);

    // 6. catT[:, :256] = qryTb + refsT @ Wproj^T + bproj
    gemm_bt<<<dim3(2, 32, Bb_), 256, 0, stream>>>(
        refsT, Wprojb, nullptr, catT, Nn_, C, C, C, C, 2 * C,
        MN, 0, (long)Nn_ * 2 * C,
        nullptr, bproj, 0, nullptr, qryTb, C, MN, 1.0f, 0);

    // 7. catT[:, 256:] = fused cross attention (+qryTb, +bout)
    cross_fused<<<Bb_ * (Nn_ / 64), 256, 0, stream>>>(
        x2T, qryTb, ktil, betab, vtil, bout, catT);

    // 8. implicit conv3x3 (9-way tap-split, bf16 partials) + reduce(relu)
    conv3x3_gemm<<<dim3(2, 32, Bb_ * 9), 256, 0, stream>>>(catT, Wtap, convPart);
    for (int b = 0; b < Bb_; ++b)
        reduce_partials<<<(int)(MN / 1024), 256, 0, stream>>>(
            convPart + (long)b * 9 * MN, MN, y1T + (long)b * MN, MN);

    // 9. out = qry + Wf2 @ y1 + bf2   (fp32 [B][C][N])
    gemm_bt<<<dim3(32, 2, Bb_), 256, 0, stream>>>(
        Wf2b, y1T, out, nullptr, C, Nn_, C, C, C, Nn_,
        0, MN, CN,
        bf2, nullptr, 0, qry, nullptr, Nn_, CN, 1.0f, 0);
}

// Round 16
// 220.028 us; speedup vs baseline: 1.4415x; 1.4415x over previous
//
#include <hip/hip_runtime.h>
#include <hip/hip_bf16.h>

#define C 256
#define HID 128
#define Bb_ 2
#define Hh 64
#define Ww 64
#define Nn_ 4096
#define NP 16
#define NC 16
#define KVSPLIT 8
#define KVB 32

typedef __bf16 bf16x8 __attribute__((ext_vector_type(8)));
typedef float f32x4 __attribute__((ext_vector_type(4)));

// ---------------------------------------------------------------------------
// Coalesced tiled LayerNorm -> x1T, x2T bf16 [B][N][C]; also emits qryT bf16.
__global__ __launch_bounds__(256) void lnT_kernel(
    const float* __restrict__ x,
    const float* __restrict__ g1, const float* __restrict__ b1,
    const float* __restrict__ g2, const float* __restrict__ b2,
    __hip_bfloat16* __restrict__ x1T, __hip_bfloat16* __restrict__ x2T,
    __hip_bfloat16* __restrict__ qryTb)
{
    int blk = blockIdx.x;
    int b = blk >> 6;
    int n0 = (blk & 63) << 6;
    int t = threadIdx.x;
    __shared__ __hip_bfloat16 xs[64][258];
    __shared__ float rs4[4][64], rq4[4][64], mean[64], inv[64];
    int j = t & 63, cg = t >> 6;
    float s = 0.f, q = 0.f;
    for (int it = 0; it < 64; ++it) {
        int c = it * 4 + cg;
        float v = x[((long)b * C + c) * Nn_ + n0 + j];
        xs[j][c] = __float2bfloat16(v);
        s += v; q += v * v;
    }
    rs4[cg][j] = s; rq4[cg][j] = q;
    __syncthreads();
    if (t < 64) {
        float S = rs4[0][t] + rs4[1][t] + rs4[2][t] + rs4[3][t];
        float Q = rq4[0][t] + rq4[1][t] + rq4[2][t] + rq4[3][t];
        float m = S * (1.0f / C);
        float var = Q * (1.0f / C) - m * m;
        mean[t] = m; inv[t] = rsqrtf(var + 1e-5f);
    }
    __syncthreads();
    float G1 = g1[t], B1 = b1[t], G2 = g2[t], B2 = b2[t];
    for (int j2 = 0; j2 < 64; ++j2) {
        float v = __bfloat162float(xs[j2][t]);
        float xn = (v - mean[j2]) * inv[j2];
        long o = ((long)b * Nn_ + n0 + j2) * C + t;
        x1T[o] = __float2bfloat16(xn * G1 + B1);
        x2T[o] = __float2bfloat16(xn * G2 + B2);
        qryTb[o] = xs[j2][t];
    }
}

// ---------------------------------------------------------------------------
__global__ __launch_bounds__(256) void gate_kernel(
    const float* __restrict__ arch, const float* __restrict__ Wg,
    const float* __restrict__ bg, float* __restrict__ gate)
{
    int b = blockIdx.x;
    int o = threadIdx.x;
    __shared__ float guide[C];
    float s = 0.f;
    for (int p = 0; p < NP; ++p) s += arch[(long)b * NP * C + (long)p * C + o];
    guide[o] = s * (1.0f / NP);
    __syncthreads();
    float acc = bg[o];
    for (int cc = 0; cc < C; ++cc) acc += guide[cc] * Wg[(long)o * C + cc];
    gate[b * C + o] = 1.0f / (1.0f + __expf(-acc));
}

// ---------------------------------------------------------------------------
#define QSCALE 0.09016844005429271f   // log2(e)/16
__global__ __launch_bounds__(256) void build_wqkv(
    const float* __restrict__ Wqkv, const float* __restrict__ bqkv,
    const float* __restrict__ gate,
    __hip_bfloat16* __restrict__ WqkvG, float* __restrict__ biasCol)
{
    long i = (long)blockIdx.x * 256 + threadIdx.x;
    long total = (long)Bb_ * 3 * C * C;
    if (i < total) {
        long b = i / (3 * C * C);
        long rem = i % (3 * C * C);
        int o = (int)(rem / C);
        float v = Wqkv[rem];
        if (o < C) v *= QSCALE;
        else if (o < 2 * C) v *= gate[b * C + (o - C)];
        WqkvG[i] = __float2bfloat16(v);
    }
    if (i < (long)Bb_ * 3 * C) {
        long b = i / (3 * C);
        int o = (int)(i % (3 * C));
        float v = bqkv[o];
        if (o < C) v *= QSCALE;
        else if (o < 2 * C) v *= gate[b * C + (o - C)];
        biasCol[i] = v;
    }
}

// ---------------------------------------------------------------------------
// Cast Wproj, Wf2 to bf16 and build Wtap [9][O][512] from Wf1.
__global__ __launch_bounds__(256) void cast_all(
    const float* __restrict__ Wproj, const float* __restrict__ Wf2,
    const float* __restrict__ Wf1,
    __hip_bfloat16* __restrict__ Wprojb, __hip_bfloat16* __restrict__ Wf2b,
    __hip_bfloat16* __restrict__ Wtap)
{
    long i = (long)blockIdx.x * 256 + threadIdx.x;
    const long nP = (long)C * C;
    const long nT = 9l * C * 2 * C;
    if (i < nP) { Wprojb[i] = __float2bfloat16(Wproj[i]); return; }
    i -= nP;
    if (i < nP) { Wf2b[i] = __float2bfloat16(Wf2[i]); return; }
    i -= nP;
    if (i < nT) {
        int tap = (int)(i / (C * 2 * C));
        long rem = i % (C * 2 * C);
        int o = (int)(rem / (2 * C)), ic = (int)(rem % (2 * C));
        Wtap[i] = __float2bfloat16(Wf1[((long)o * 2 * C + ic) * 9 + tap]);
    }
}

// ---------------------------------------------------------------------------
// Cross-attention algebraic prep (fold Wq/Wout through the 16-token attn).
__global__ __launch_bounds__(256) void cross_prep(
    const float* __restrict__ ctx, const float* __restrict__ Wkv,
    const float* __restrict__ bkv, const float* __restrict__ Wq,
    const float* __restrict__ bq, const float* __restrict__ Wout,
    float* __restrict__ ktil, float* __restrict__ beta,
    float* __restrict__ vtil)
{
    int b = blockIdx.x >> 4, m = blockIdx.x & 15;
    int t = threadIdx.x;
    __shared__ float cs[C], kl[C], red[128];
    cs[t] = ctx[((long)b * NC + m) * C + t];
    __syncthreads();
    float acc = bkv[t];
    for (int c = 0; c < C; ++c) acc += cs[c] * Wkv[(long)t * C + c];
    kl[t] = acc;
    __syncthreads();
    const float scc = 0.08838834764831845f;
    float kt = 0.f;
    for (int h = 0; h < HID; ++h) kt += kl[h] * Wq[(long)h * C + t];
    ktil[((long)b * NC + m) * C + t] = kt * scc;
    float vt = 0.f;
    for (int h = 0; h < HID; ++h) vt += kl[HID + h] * Wout[(long)t * HID + h];
    vtil[((long)b * C + t) * NC + m] = vt;
    if (t < 128) red[t] = bq[t] * kl[t];
    __syncthreads();
    for (int s = 64; s > 0; s >>= 1) {
        if (t < s) red[t] += red[t + s];
        __syncthreads();
    }
    if (t == 0) beta[b * NC + m] = red[0] * scc;
}

// ---------------------------------------------------------------------------
// Fused cross attention -> catT right half (qryT bf16)
__global__ __launch_bounds__(256) void cross_fused(
    const __hip_bfloat16* __restrict__ x2T, const __hip_bfloat16* __restrict__ qryTb,
    const float* __restrict__ ktil, const float* __restrict__ beta,
    const float* __restrict__ vtil, const float* __restrict__ bout,
    __hip_bfloat16* __restrict__ catT)
{
    int blk = blockIdx.x;
    int b = blk >> 6;
    long n = (long)(blk & 63) * 64 + (threadIdx.x >> 2);
    int cg = threadIdx.x & 3;
    int t = threadIdx.x;
    __shared__ float kt[NC * C];
    __shared__ float vt[C * NC];
    for (int r = 0; r < 16; ++r) {
        int idx = r * 256 + t;
        int m = idx >> 8, c = idx & 255;
        kt[m * 256 + (c & 63) * 4 + (c >> 6)] = ktil[((long)b * NC + m) * C + c];
        int c2 = idx >> 4, m2 = idx & 15;
        vt[((c2 & 63) * 4 + (c2 >> 6)) * 16 + m2] = vtil[((long)b * C + c2) * NC + m2];
    }
    __syncthreads();

    float s[NC];
    #pragma unroll
    for (int m = 0; m < NC; ++m) s[m] = 0.f;
    const __hip_bfloat16* xr = x2T + ((long)b * Nn_ + n) * C + cg * 64;
    for (int c8 = 0; c8 < 8; ++c8) {
        bf16x8 xv = *(const bf16x8*)(xr + c8 * 8);
        #pragma unroll
        for (int e = 0; e < 8; ++e) {
            float xf = (float)xv[e];
            int ic = c8 * 8 + e;
            #pragma unroll
            for (int m = 0; m < NC; ++m)
                s[m] += xf * kt[m * 256 + ic * 4 + cg];
        }
    }
    #pragma unroll
    for (int m = 0; m < NC; ++m) {
        s[m] += __shfl_xor(s[m], 1);
        s[m] += __shfl_xor(s[m], 2);
        s[m] += beta[b * NC + m];
    }
    float mx = -1e30f;
    #pragma unroll
    for (int m = 0; m < NC; ++m) mx = fmaxf(mx, s[m]);
    float sum = 0.f;
    #pragma unroll
    for (int m = 0; m < NC; ++m) { s[m] = __expf(s[m] - mx); sum += s[m]; }
    float dn = 1.0f / sum;

    const __hip_bfloat16* qr = qryTb + ((long)b * Nn_ + n) * C + cg * 64;
    __hip_bfloat16* outp = catT + ((long)b * Nn_ + n) * (2 * C) + C + cg * 64;
    for (int c8 = 0; c8 < 8; ++c8) {
        union { ushort4 u; __hip_bfloat16 h[4]; } cv0, cv1;
        #pragma unroll
        for (int e = 0; e < 8; ++e) {
            int ic = c8 * 8 + e;
            int c = cg * 64 + ic;
            float acc = __bfloat162float(qr[ic]) + bout[c];
            float pv = 0.f;
            #pragma unroll
            for (int m = 0; m < NC; ++m)
                pv += vt[(ic * 4 + cg) * 16 + m] * s[m];
            acc += pv * dn;
            if (e < 4) cv0.h[e] = __float2bfloat16(acc);
            else       cv1.h[e - 4] = __float2bfloat16(acc);
        }
        *(ushort4*)(outp + c8 * 8) = cv0.u;
        *(ushort4*)(outp + c8 * 8 + 4) = cv1.u;
    }
}

// ---------------------------------------------------------------------------
// 64x64-tile MFMA bf16 GEMM for the small projection GEMMs (high occupancy:
// 8KB LDS, ~64 VGPR). 4 waves in 2x2; each wave 32x32 via 2x2 16x16x32 frags.
__global__ __launch_bounds__(256) void gemm64(
    const __hip_bfloat16* __restrict__ A,
    const __hip_bfloat16* __restrict__ Bt,
    float* __restrict__ D,
    __hip_bfloat16* __restrict__ Dbf,
    int M, int N, int K, int lda, int ldb, int ldd,
    long batchA, long batchB, long batchD,
    const float* __restrict__ biasRow,
    const float* __restrict__ biasCol, long bcStride,
    const float* __restrict__ resid,
    const __hip_bfloat16* __restrict__ residB, int ldr, long batchR,
    float alpha, int relu)
{
    __shared__ __align__(16) __hip_bfloat16 As[64 * 32];
    __shared__ __align__(16) __hip_bfloat16 Bs[64 * 32];
    int bz = blockIdx.z;
    const __hip_bfloat16* Ab = A + (long)bz * batchA;
    const __hip_bfloat16* Bb = Bt + (long)bz * batchB;
    int m0 = blockIdx.y * 64, n0 = blockIdx.x * 64;
    int tid = threadIdx.x;
    int lane = tid & 63, wave = tid >> 6;
    int wr = wave >> 1, wc = wave & 1;
    int lr = lane & 15, lg = lane >> 4;
    int srow = tid >> 2, ske = (tid & 3) * 8;

    f32x4 acc[2][2];
    #pragma unroll
    for (int i = 0; i < 2; ++i)
        #pragma unroll
        for (int j = 0; j < 2; ++j)
            #pragma unroll
            for (int r = 0; r < 4; ++r) acc[i][j][r] = 0.f;

    for (int k0 = 0; k0 < K; k0 += 32) {
        uint4 va = *(const uint4*)(Ab + (long)(m0 + srow) * lda + k0 + ske);
        uint4 vb = *(const uint4*)(Bb + (long)(n0 + srow) * ldb + k0 + ske);
        ((uint4*)As)[tid] = va;
        ((uint4*)Bs)[tid] = vb;
        __syncthreads();
        bf16x8 af[2], bfr[2];
        #pragma unroll
        for (int i = 0; i < 2; ++i)
            af[i] = *(const bf16x8*)(As + (wr * 32 + i * 16 + lr) * 32 + lg * 8);
        #pragma unroll
        for (int j = 0; j < 2; ++j)
            bfr[j] = *(const bf16x8*)(Bs + (wc * 32 + j * 16 + lr) * 32 + lg * 8);
        #pragma unroll
        for (int i = 0; i < 2; ++i)
            #pragma unroll
            for (int j = 0; j < 2; ++j)
                acc[i][j] = __builtin_amdgcn_mfma_f32_16x16x32_bf16(af[i], bfr[j], acc[i][j], 0, 0, 0);
        __syncthreads();
    }

    int colc = n0 + wc * 32 + lr;
    #pragma unroll
    for (int i = 0; i < 2; ++i) {
        #pragma unroll
        for (int r = 0; r < 4; ++r) {
            int row = m0 + wr * 32 + i * 16 + lg * 4 + r;
            float brv = biasRow ? biasRow[row] : 0.f;
            #pragma unroll
            for (int j = 0; j < 2; ++j) {
                int cc = colc + j * 16;
                float v = acc[i][j][r] * alpha + brv;
                if (biasCol) v += biasCol[bz * bcStride + cc];
                if (resid) v += resid[(long)bz * batchR + (long)row * ldr + cc];
                if (residB) v += __bfloat162float(residB[(long)bz * batchR + (long)row * ldr + cc]);
                if (relu) v = fmaxf(v, 0.f);
                long oa = (long)bz * batchD + (long)row * ldd + cc;
                if (Dbf) Dbf[oa] = __float2bfloat16(v);
                else     D[oa] = v;
            }
        }
    }
}

// ---------------------------------------------------------------------------
__global__ __launch_bounds__(256) void extract_v(
    const __hip_bfloat16* __restrict__ qkvT, __hip_bfloat16* __restrict__ vB)
{
    int b = blockIdx.z;
    int c0 = blockIdx.y * 64, m0 = blockIdx.x * 64;
    __shared__ __hip_bfloat16 tb[64][66];
    int tx = threadIdx.x & 63, tg = threadIdx.x >> 6;
    for (int rr = tg; rr < 64; rr += 4)
        tb[rr][tx] = qkvT[((long)b * Nn_ + m0 + rr) * (3 * C) + 2 * C + c0 + tx];
    __syncthreads();
    for (int rr = tg; rr < 64; rr += 4)
        vB[((long)b * C + c0 + rr) * Nn_ + m0 + tx] = tb[tx][rr];
}

// ---------------------------------------------------------------------------
// Flash attention (round-12 version, best measured: 70us).
// KVB=32 -> 36KB LDS -> 4 blocks/CU. XOR-swizzled LDS; bf16 Opart.
__global__ __launch_bounds__(256) void flash_attn(
    const __hip_bfloat16* __restrict__ qkvT,
    const __hip_bfloat16* __restrict__ vB,
    __hip_bfloat16* __restrict__ Opart,   // [B][KVSPLIT][N][256] bf16
    float* __restrict__ lsum)             // [B][KVSPLIT][N]
{
    int qb = blockIdx.x, sp = blockIdx.y, b = blockIdx.z;
    int n0 = qb * 64;
    int tid = threadIdx.x;
    int lane = tid & 63, w = tid >> 6;
    int lr = lane & 15, lg = lane >> 4;

    __shared__ __align__(16) char Ks[32 * 512];
    __shared__ __align__(16) char Vs[128 * 128];
    __shared__ __align__(16) char Pl[32 * 128];

    bf16x8 qf[8];
    {
        const __hip_bfloat16* qp = qkvT + ((long)b * Nn_ + n0 + w * 16 + lr) * (3 * C);
        #pragma unroll
        for (int ks = 0; ks < 8; ++ks)
            qf[ks] = *(const bf16x8*)(qp + ks * 32 + lg * 8);
    }

    const __hip_bfloat16* kbase = qkvT + ((long)b * Nn_) * (3 * C) + C;
    const __hip_bfloat16* vbase = vB + (long)b * C * Nn_;
    int kvBeg = sp * (Nn_ / KVSPLIT);

    int krow[4], kc[4], koff[4], vd[4], vc[4], voff[4];
    #pragma unroll
    for (int ps = 0; ps < 4; ++ps) {
        int id = ps * 256 + tid;
        krow[ps] = id >> 5; kc[ps] = id & 31;
        koff[ps] = krow[ps] * 512 + ((kc[ps] * 16) ^ ((krow[ps] & 7) << 4));
        vd[ps] = id >> 2; vc[ps] = id & 3;
        int vp = vd[ps] >> 1;
        voff[ps] = vp * 128 + ((((vd[ps] & 1) * 64) + vc[ps] * 16) ^ ((vp & 7) << 4));
    }

    f32x4 Oacc[16];
    #pragma unroll
    for (int jd = 0; jd < 16; ++jd)
        #pragma unroll
        for (int r = 0; r < 4; ++r) Oacc[jd][r] = 0.f;
    float l_r[4] = {0.f, 0.f, 0.f, 0.f};

    const int NT = (Nn_ / KVSPLIT) / KVB;   // 16
    for (int t = 0; t < NT; ++t) {
        int kv0 = kvBeg + t * KVB;
        uint4 kr[4], vr[4];
        #pragma unroll
        for (int ps = 0; ps < 4; ++ps) {
            kr[ps] = *(const uint4*)(kbase + (long)(kv0 + krow[ps]) * (3 * C) + kc[ps] * 8);
            vr[ps] = *(const uint4*)(vbase + (long)vd[ps] * Nn_ + kv0 + vc[ps] * 8);
        }
        #pragma unroll
        for (int ps = 0; ps < 4; ++ps) {
            *(uint4*)(Ks + koff[ps]) = kr[ps];
            *(uint4*)(Vs + voff[ps]) = vr[ps];
        }
        __syncthreads();
        // ---- S = Q K^T (log2-domain)
        f32x4 sacc[2];
        #pragma unroll
        for (int j = 0; j < 2; ++j)
            #pragma unroll
            for (int r = 0; r < 4; ++r) sacc[j][r] = 0.f;
        __builtin_amdgcn_s_setprio(1);
        #pragma unroll
        for (int ks = 0; ks < 8; ++ks) {
            #pragma unroll
            for (int j = 0; j < 2; ++j) {
                int row = j * 16 + lr;
                bf16x8 kf = *(const bf16x8*)(Ks + row * 512 +
                            ((ks * 64 + lg * 16) ^ ((row & 7) << 4)));
                sacc[j] = __builtin_amdgcn_mfma_f32_16x16x32_bf16(qf[ks], kf, sacc[j], 0, 0, 0);
            }
        }
        __builtin_amdgcn_s_setprio(0);
        // ---- P = exp2(S) -> Pl
        #pragma unroll
        for (int j = 0; j < 2; ++j)
            #pragma unroll
            for (int r = 0; r < 4; ++r) {
                float p = __builtin_amdgcn_exp2f(sacc[j][r]);
                l_r[r] += p;
                int prow = w * 16 + 4 * lg + r;
                int pp = prow >> 1;
                *(__hip_bfloat16*)(Pl + pp * 128 +
                    ((((prow & 1) * 64) + (j * 16 + lr) * 2) ^ ((pp & 7) << 4))) =
                    __float2bfloat16(p);
            }
        // ---- O += P V^T
        __builtin_amdgcn_s_setprio(1);
        {
            int prow = w * 16 + lr;
            int pp = prow >> 1;
            bf16x8 pf = *(const bf16x8*)(Pl + pp * 128 +
                        ((((prow & 1) * 64) + lg * 16) ^ ((pp & 7) << 4)));
            #pragma unroll
            for (int jd = 0; jd < 16; ++jd) {
                int vrw = jd * 16 + lr;
                int vp = vrw >> 1;
                bf16x8 vf = *(const bf16x8*)(Vs + vp * 128 +
                            ((((vrw & 1) * 64) + lg * 16) ^ ((vp & 7) << 4)));
                Oacc[jd] = __builtin_amdgcn_mfma_f32_16x16x32_bf16(pf, vf, Oacc[jd], 0, 0, 0);
            }
        }
        __builtin_amdgcn_s_setprio(0);
        __syncthreads();
    }

    #pragma unroll
    for (int r = 0; r < 4; ++r) {
        float v = l_r[r];
        #pragma unroll
        for (int off = 1; off <= 8; off <<= 1)
            v += __shfl_xor(v, off);
        l_r[r] = v;
    }

    __hip_bfloat16* Op = Opart + (((long)b * KVSPLIT + sp) * Nn_ + n0) * 256;
    #pragma unroll
    for (int jd = 0; jd < 16; ++jd)
        #pragma unroll
        for (int r = 0; r < 4; ++r) {
            int row = w * 16 + lg * 4 + r;
            Op[(long)row * 256 + jd * 16 + lr] = __float2bfloat16(Oacc[jd][r]);
        }
    if (lr == 0) {
        float* lp = lsum + ((long)b * KVSPLIT + sp) * Nn_ + n0;
        #pragma unroll
        for (int r = 0; r < 4; ++r)
            lp[w * 16 + lg * 4 + r] = l_r[r];
    }
}

// ---------------------------------------------------------------------------
__global__ __launch_bounds__(256) void merge_flash(
    const __hip_bfloat16* __restrict__ Opart, const float* __restrict__ lsum,
    __hip_bfloat16* __restrict__ refsT)
{
    long gi = (long)blockIdx.x * 256 + threadIdx.x;
    long row = gi >> 6;
    int c4 = (int)(gi & 63) * 4;
    long b = row / Nn_, n = row % Nn_;
    float l = 0.f;
    float o0 = 0.f, o1 = 0.f, o2 = 0.f, o3 = 0.f;
    #pragma unroll
    for (int sp = 0; sp < KVSPLIT; ++sp) {
        long rr = (b * KVSPLIT + sp) * Nn_ + n;
        l += lsum[rr];
        union { ushort4 u; __hip_bfloat16 h[4]; } rv;
        rv.u = *(const ushort4*)(Opart + rr * 256 + c4);
        o0 += __bfloat162float(rv.h[0]);
        o1 += __bfloat162float(rv.h[1]);
        o2 += __bfloat162float(rv.h[2]);
        o3 += __bfloat162float(rv.h[3]);
    }
    float dn = 1.0f / l;
    union { ushort4 u; __hip_bfloat16 h[4]; } cv;
    cv.h[0] = __float2bfloat16(o0 * dn);
    cv.h[1] = __float2bfloat16(o1 * dn);
    cv.h[2] = __float2bfloat16(o2 * dn);
    cv.h[3] = __float2bfloat16(o3 * dn);
    *(ushort4*)(refsT + (b * Nn_ + n) * 256 + c4) = cv.u;
}

// ---------------------------------------------------------------------------
// Implicit-GEMM 3x3 conv, 9-way tap-split (1152 blocks). partials bf16.
__global__ __launch_bounds__(256) void conv3x3_gemm(
    const __hip_bfloat16* __restrict__ catT,
    const __hip_bfloat16* __restrict__ Wtap,
    __hip_bfloat16* __restrict__ partials)
{
    __shared__ __align__(16) __hip_bfloat16 As[128 * 32];
    __shared__ __align__(16) __hip_bfloat16 Bs[128 * 32];
    int z = blockIdx.z;
    int b = z / 9, sp = z % 9;
    int dh = sp / 3 - 1, dw = sp % 3 - 1;
    int o0 = blockIdx.x * 128, m0 = blockIdx.y * 128;
    int tid = threadIdx.x;
    int lane = tid & 63, wave = tid >> 6;
    int wr = wave >> 1, wc = wave & 1;
    int lr = lane & 15, lg = lane >> 4;
    const __hip_bfloat16* cb = catT + (long)b * Nn_ * (2 * C);
    const __hip_bfloat16* wt = Wtap + (long)sp * C * (2 * C);

    f32x4 acc[4][4];
    #pragma unroll
    for (int i = 0; i < 4; ++i)
        #pragma unroll
        for (int j = 0; j < 4; ++j)
            #pragma unroll
            for (int r = 0; r < 4; ++r) acc[i][j][r] = 0.f;

    for (int k0 = 0; k0 < 2 * C; k0 += 32) {
        #pragma unroll
        for (int q = 0; q < 2; ++q) {
            int idx = q * 256 + tid;
            int row = idx >> 2;
            int ke = (idx & 3) * 8;
            int gm = m0 + row;
            int h = (gm >> 6) + dh, w2 = (gm & 63) + dw;
            uint4 va = {0, 0, 0, 0};
            if ((unsigned)h < 64u && (unsigned)w2 < 64u)
                va = *(const uint4*)(cb + ((long)((h << 6) + w2)) * (2 * C) + k0 + ke);
            ((uint4*)As)[idx] = va;
            ((uint4*)Bs)[idx] = *(const uint4*)(wt + (long)(o0 + row) * (2 * C) + k0 + ke);
        }
        __syncthreads();
        bf16x8 af[4], bfr[4];
        #pragma unroll
        for (int i = 0; i < 4; ++i)
            af[i] = *(const bf16x8*)(As + (wr * 64 + i * 16 + lr) * 32 + lg * 8);
        #pragma unroll
        for (int j = 0; j < 4; ++j)
            bfr[j] = *(const bf16x8*)(Bs + (wc * 64 + j * 16 + lr) * 32 + lg * 8);
        #pragma unroll
        for (int i = 0; i < 4; ++i)
            #pragma unroll
            for (int j = 0; j < 4; ++j)
                acc[i][j] = __builtin_amdgcn_mfma_f32_16x16x32_bf16(af[i], bfr[j], acc[i][j], 0, 0, 0);
        __syncthreads();
    }

    __hip_bfloat16* Dp = partials + ((long)(b * 9 + sp) * Nn_ + m0) * 256;
    #pragma unroll
    for (int i = 0; i < 4; ++i)
        #pragma unroll
        for (int r = 0; r < 4; ++r) {
            int row = wr * 64 + i * 16 + lg * 4 + r;
            #pragma unroll
            for (int j = 0; j < 4; ++j)
                Dp[(long)row * 256 + o0 + wc * 64 + j * 16 + lr] =
                    __float2bfloat16(acc[i][j][r]);
        }
}

// ---------------------------------------------------------------------------
__global__ __launch_bounds__(256) void reduce_partials(
    const __hip_bfloat16* __restrict__ part, long partStride,
    __hip_bfloat16* __restrict__ out, long n)
{
    long i = ((long)blockIdx.x * 256 + threadIdx.x) * 4;
    if (i >= n) return;
    float a[4] = {0.f, 0.f, 0.f, 0.f};
    #pragma unroll
    for (int sp = 0; sp < 9; ++sp) {
        union { ushort4 u; __hip_bfloat16 h[4]; } rv;
        rv.u = *(const ushort4*)(part + (long)sp * partStride + i);
        #pragma unroll
        for (int k = 0; k < 4; ++k) a[k] += __bfloat162float(rv.h[k]);
    }
    union { ushort4 u; __hip_bfloat16 h[4]; } cv;
    #pragma unroll
    for (int k = 0; k < 4; ++k)
        cv.h[k] = __float2bfloat16(fmaxf(a[k], 0.f));
    *(ushort4*)(out + i) = cv.u;
}

// ---------------------------------------------------------------------------
extern "C" void kernel_launch(void* const* d_in, const int* in_sizes, int n_in,
                              void* d_out, int out_size, void* d_ws, size_t ws_size,
                              hipStream_t stream)
{
    const float* qry   = (const float*)d_in[0];
    const float* arch  = (const float*)d_in[1];
    const float* ctx   = (const float*)d_in[2];
    const float* ln1_g = (const float*)d_in[3];
    const float* ln1_b = (const float*)d_in[4];
    const float* Wqkv  = (const float*)d_in[5];
    const float* bqkv  = (const float*)d_in[6];
    const float* Wproj = (const float*)d_in[7];
    const float* bproj = (const float*)d_in[8];
    const float* Wg    = (const float*)d_in[9];
    const float* bg    = (const float*)d_in[10];
    const float* ln2_g = (const float*)d_in[11];
    const float* ln2_b = (const float*)d_in[12];
    const float* Wq    = (const float*)d_in[13];
    const float* bq    = (const float*)d_in[14];
    const float* Wkv   = (const float*)d_in[15];
    const float* bkv   = (const float*)d_in[16];
    const float* Wout  = (const float*)d_in[17];
    const float* bout  = (const float*)d_in[18];
    const float* Wf1   = (const float*)d_in[19];
    const float* Wf2   = (const float*)d_in[20];
    const float* bf2   = (const float*)d_in[21];
    float* out = (float*)d_out;

    const long CN = (long)C * Nn_;
    const long MN = (long)Nn_ * C;
    char* ws = (char*)d_ws;
    size_t off = 0;
    auto alloc = [&](size_t bytes) -> char* {
        char* p = ws + off;
        off += (bytes + 255) & ~size_t(255);
        return p;
    };
    float* lbuf     = (float*)alloc((long)Bb_ * KVSPLIT * Nn_ * 4);
    float* gate     = (float*)alloc(Bb_ * C * 4);
    float* biasCol  = (float*)alloc((long)Bb_ * 3 * C * 4);
    float* ktil     = (float*)alloc((long)Bb_ * NC * C * 4);
    float* betab    = (float*)alloc((long)Bb_ * NC * 4);
    float* vtil     = (float*)alloc((long)Bb_ * C * NC * 4);
    __hip_bfloat16* Opart = (__hip_bfloat16*)alloc((long)Bb_ * KVSPLIT * MN * 2);
    __hip_bfloat16* convPart = (__hip_bfloat16*)alloc((long)Bb_ * 9 * MN * 2);
    __hip_bfloat16* qryTb = (__hip_bfloat16*)alloc(Bb_ * MN * 2);
    __hip_bfloat16* x1T   = (__hip_bfloat16*)alloc(Bb_ * MN * 2);
    __hip_bfloat16* x2T   = (__hip_bfloat16*)alloc(Bb_ * MN * 2);
    __hip_bfloat16* qkvT  = (__hip_bfloat16*)alloc((long)Bb_ * Nn_ * 3 * C * 2);
    __hip_bfloat16* vB    = (__hip_bfloat16*)alloc(Bb_ * CN * 2);
    __hip_bfloat16* refsT = (__hip_bfloat16*)alloc(Bb_ * MN * 2);
    __hip_bfloat16* catT  = (__hip_bfloat16*)alloc((long)Bb_ * Nn_ * 2 * C * 2);
    __hip_bfloat16* y1T   = (__hip_bfloat16*)alloc(Bb_ * MN * 2);
    __hip_bfloat16* WqkvG = (__hip_bfloat16*)alloc((long)Bb_ * 3 * C * C * 2);
    __hip_bfloat16* Wprojb= (__hip_bfloat16*)alloc((long)C * C * 2);
    __hip_bfloat16* Wf2b  = (__hip_bfloat16*)alloc((long)C * C * 2);
    __hip_bfloat16* Wtap  = (__hip_bfloat16*)alloc((long)9 * C * 2 * C * 2);

    // 1. layernorm (+ bf16 qry transpose fused)
    lnT_kernel<<<Bb_ * (Nn_ / 64), 256, 0, stream>>>(
        qry, ln1_g, ln1_b, ln2_g, ln2_b, x1T, x2T, qryTb);

    // 2. gate + weight prep + cross prep
    gate_kernel<<<Bb_, 256, 0, stream>>>(arch, Wg, bg, gate);
    build_wqkv<<<(Bb_ * 3 * C * C + 255) / 256, 256, 0, stream>>>(Wqkv, bqkv, gate, WqkvG, biasCol);
    {
        long total = (long)C * C * 2 + 9l * C * 2 * C;
        cast_all<<<(int)((total + 255) / 256), 256, 0, stream>>>(
            Wproj, Wf2, Wf1, Wprojb, Wf2b, Wtap);
    }
    cross_prep<<<Bb_ * NC, 256, 0, stream>>>(ctx, Wkv, bkv, Wq, bq, Wout, ktil, betab, vtil);

    // 3. qkvT = x1T @ WqkvG^T + biasCol  -> bf16 [B][N][768]  (64x64 tiles)
    gemm64<<<dim3(3 * C / 64, Nn_ / 64, Bb_), 256, 0, stream>>>(
        x1T, WqkvG, nullptr, qkvT, Nn_, 3 * C, C, C, C, 3 * C,
        MN, (long)3 * C * C, (long)Nn_ * 3 * C,
        nullptr, biasCol, 3 * C, nullptr, nullptr, 0, 0, 1.0f, 0);

    // 4. v -> vB [B][C][N]
    extract_v<<<dim3(Nn_ / 64, C / 64, Bb_), 256, 0, stream>>>(qkvT, vB);

    // 5. flash attention + merge -> refsT bf16 [B][N][C]
    flash_attn<<<dim3(Nn_ / 64, KVSPLIT, Bb_), 256, 0, stream>>>(qkvT, vB, Opart, lbuf);
    merge_flash<<<(int)((long)Bb_ * Nn_ * 64 / 256), 256, 0, stream>>>(Opart, lbuf, refsT);

    // 6. catT[:, :256] = qryTb + refsT @ Wproj^T + bproj  (64x64 tiles)
    gemm64<<<dim3(C / 64, Nn_ / 64, Bb_), 256, 0, stream>>>(
        refsT, Wprojb, nullptr, catT, Nn_, C, C, C, C, 2 * C,
        MN, 0, (long)Nn_ * 2 * C,
        nullptr, bproj, 0, nullptr, qryTb, C, MN, 1.0f, 0);

    // 7. catT[:, 256:] = fused cross attention (+qryTb, +bout)
    cross_fused<<<Bb_ * (Nn_ / 64), 256, 0, stream>>>(
        x2T, qryTb, ktil, betab, vtil, bout, catT);

    // 8. implicit conv3x3 (9-way tap-split, bf16 partials) + reduce(relu)
    conv3x3_gemm<<<dim3(2, 32, Bb_ * 9), 256, 0, stream>>>(catT, Wtap, convPart);
    for (int b = 0; b < Bb_; ++b)
        reduce_partials<<<(int)(MN / 1024), 256, 0, stream>>>(
            convPart + (long)b * 9 * MN, MN, y1T + (long)b * MN, MN);

    // 9. out = qry + Wf2 @ y1 + bf2   (fp32 [B][C][N])  (64x64 tiles)
    gemm64<<<dim3(Nn_ / 64, C / 64, Bb_), 256, 0, stream>>>(
        Wf2b, y1T, out, nullptr, C, Nn_, C, C, C, Nn_,
        0, MN, CN,
        bf2, nullptr, 0, qry, nullptr, Nn_, CN, 1.0f, 0);
}

// Round 17
// 218.138 us; speedup vs baseline: 1.4540x; 1.0087x over previous
//
#include <hip/hip_runtime.h>
#include <hip/hip_bf16.h>

#define C 256
#define HID 128
#define Bb_ 2
#define Hh 64
#define Ww 64
#define Nn_ 4096
#define NP 16
#define NC 16
#define KVSPLIT 8
#define KVB 32

typedef __bf16 bf16x8 __attribute__((ext_vector_type(8)));
typedef float f32x4 __attribute__((ext_vector_type(4)));

// ---------------------------------------------------------------------------
// Coalesced tiled LayerNorm -> x1T bf16 [B][N][C], qryT bf16, mean/inv fp32.
// (x2T eliminated: ln2 is folded algebraically into cross_prep/cross_fused.)
__global__ __launch_bounds__(256) void lnT_kernel(
    const float* __restrict__ x,
    const float* __restrict__ g1, const float* __restrict__ b1,
    __hip_bfloat16* __restrict__ x1T, __hip_bfloat16* __restrict__ qryTb,
    float* __restrict__ meanb, float* __restrict__ invb)
{
    int blk = blockIdx.x;
    int b = blk >> 6;
    int n0 = (blk & 63) << 6;
    int t = threadIdx.x;
    __shared__ __hip_bfloat16 xs[64][258];
    __shared__ float rs4[4][64], rq4[4][64], mean[64], inv[64];
    int j = t & 63, cg = t >> 6;
    float s = 0.f, q = 0.f;
    for (int it = 0; it < 64; ++it) {
        int c = it * 4 + cg;
        float v = x[((long)b * C + c) * Nn_ + n0 + j];
        xs[j][c] = __float2bfloat16(v);
        s += v; q += v * v;
    }
    rs4[cg][j] = s; rq4[cg][j] = q;
    __syncthreads();
    if (t < 64) {
        float S = rs4[0][t] + rs4[1][t] + rs4[2][t] + rs4[3][t];
        float Q = rq4[0][t] + rq4[1][t] + rq4[2][t] + rq4[3][t];
        float m = S * (1.0f / C);
        float var = Q * (1.0f / C) - m * m;
        mean[t] = m; inv[t] = rsqrtf(var + 1e-5f);
        meanb[(long)b * Nn_ + n0 + t] = m;
        invb[(long)b * Nn_ + n0 + t] = inv[t];
    }
    __syncthreads();
    float G1 = g1[t], B1 = b1[t];
    for (int j2 = 0; j2 < 64; ++j2) {
        float v = __bfloat162float(xs[j2][t]);
        float xn = (v - mean[j2]) * inv[j2];
        long o = ((long)b * Nn_ + n0 + j2) * C + t;
        x1T[o] = __float2bfloat16(xn * G1 + B1);
        qryTb[o] = xs[j2][t];
    }
}

// ---------------------------------------------------------------------------
__global__ __launch_bounds__(256) void gate_kernel(
    const float* __restrict__ arch, const float* __restrict__ Wg,
    const float* __restrict__ bg, float* __restrict__ gate)
{
    int b = blockIdx.x;
    int o = threadIdx.x;
    __shared__ float guide[C];
    float s = 0.f;
    for (int p = 0; p < NP; ++p) s += arch[(long)b * NP * C + (long)p * C + o];
    guide[o] = s * (1.0f / NP);
    __syncthreads();
    float acc = bg[o];
    for (int cc = 0; cc < C; ++cc) acc += guide[cc] * Wg[(long)o * C + cc];
    gate[b * C + o] = 1.0f / (1.0f + __expf(-acc));
}

// ---------------------------------------------------------------------------
#define QSCALE 0.09016844005429271f   // log2(e)/16
__global__ __launch_bounds__(256) void build_wqkv(
    const float* __restrict__ Wqkv, const float* __restrict__ bqkv,
    const float* __restrict__ gate,
    __hip_bfloat16* __restrict__ WqkvG, float* __restrict__ biasCol)
{
    long i = (long)blockIdx.x * 256 + threadIdx.x;
    long total = (long)Bb_ * 3 * C * C;
    if (i < total) {
        long b = i / (3 * C * C);
        long rem = i % (3 * C * C);
        int o = (int)(rem / C);
        float v = Wqkv[rem];
        if (o < C) v *= QSCALE;
        else if (o < 2 * C) v *= gate[b * C + (o - C)];
        WqkvG[i] = __float2bfloat16(v);
    }
    if (i < (long)Bb_ * 3 * C) {
        long b = i / (3 * C);
        int o = (int)(i % (3 * C));
        float v = bqkv[o];
        if (o < C) v *= QSCALE;
        else if (o < 2 * C) v *= gate[b * C + (o - C)];
        biasCol[i] = v;
    }
}

// ---------------------------------------------------------------------------
// Cast Wproj, Wf2 to bf16 and build Wtap [9][O][512] from Wf1.
__global__ __launch_bounds__(256) void cast_all(
    const float* __restrict__ Wproj, const float* __restrict__ Wf2,
    const float* __restrict__ Wf1,
    __hip_bfloat16* __restrict__ Wprojb, __hip_bfloat16* __restrict__ Wf2b,
    __hip_bfloat16* __restrict__ Wtap)
{
    long i = (long)blockIdx.x * 256 + threadIdx.x;
    const long nP = (long)C * C;
    const long nT = 9l * C * 2 * C;
    if (i < nP) { Wprojb[i] = __float2bfloat16(Wproj[i]); return; }
    i -= nP;
    if (i < nP) { Wf2b[i] = __float2bfloat16(Wf2[i]); return; }
    i -= nP;
    if (i < nT) {
        int tap = (int)(i / (C * 2 * C));
        long rem = i % (C * 2 * C);
        int o = (int)(rem / (2 * C)), ic = (int)(rem % (2 * C));
        Wtap[i] = __float2bfloat16(Wf1[((long)o * 2 * C + ic) * 9 + tap]);
    }
}

// ---------------------------------------------------------------------------
// Cross-attention algebraic prep with LN2 folded:
//  kl = Wkv@ctx + bkv; kt[c] = scc * sum_h kl[h]*Wq[h][c];
//  ktg[c] = kt[c]*g2[c]; sg = sum_c kt*g2; bp = scc*sum_h bq*kl + sum_c kt*b2;
//  vtil[c][m] = sum_h kl[HID+h]*Wout[c][h].
__global__ __launch_bounds__(256) void cross_prep(
    const float* __restrict__ ctx, const float* __restrict__ Wkv,
    const float* __restrict__ bkv, const float* __restrict__ Wq,
    const float* __restrict__ bq, const float* __restrict__ Wout,
    const float* __restrict__ g2, const float* __restrict__ b2,
    float* __restrict__ ktg,       // [B][NC][C]
    float* __restrict__ sgbp,      // [B][NC][2]  (sg, bp)
    float* __restrict__ vtil)      // [B][C][NC]
{
    int b = blockIdx.x >> 4, m = blockIdx.x & 15;
    int t = threadIdx.x;
    __shared__ float cs[C], kl[C], red[256];
    cs[t] = ctx[((long)b * NC + m) * C + t];
    __syncthreads();
    float acc = bkv[t];
    for (int c = 0; c < C; ++c) acc += cs[c] * Wkv[(long)t * C + c];
    kl[t] = acc;
    __syncthreads();
    const float scc = 0.08838834764831845f;  // 1/sqrt(128)
    float kt = 0.f;
    for (int h = 0; h < HID; ++h) kt += kl[h] * Wq[(long)h * C + t];
    kt *= scc;
    float G2 = g2[t], B2 = b2[t];
    ktg[((long)b * NC + m) * C + t] = kt * G2;
    float vt = 0.f;
    for (int h = 0; h < HID; ++h) vt += kl[HID + h] * Wout[(long)t * HID + h];
    vtil[((long)b * C + t) * NC + m] = vt;
    // reductions: sg = sum kt*g2 ; bp = scc*sum_{h<128} bq*kl + sum kt*b2
    red[t] = kt * G2;
    __syncthreads();
    for (int s = 128; s > 0; s >>= 1) {
        if (t < s) red[t] += red[t + s];
        __syncthreads();
    }
    float sg = red[0];
    __syncthreads();
    red[t] = kt * B2 + ((t < 128) ? scc * bq[t] * kl[t] : 0.f);
    __syncthreads();
    for (int s = 128; s > 0; s >>= 1) {
        if (t < s) red[t] += red[t + s];
        __syncthreads();
    }
    if (t == 0) {
        sgbp[(b * NC + m) * 2] = sg;
        sgbp[(b * NC + m) * 2 + 1] = red[0];
    }
}

// ---------------------------------------------------------------------------
// Fused cross attention (LN2 folded) -> catT right half.
// s[m] = inv[n]*(qryT[n]·ktg[m]) - mean[n]*inv[n]*sg[m] + bp[m]
__global__ __launch_bounds__(256) void cross_fused(
    const __hip_bfloat16* __restrict__ qryTb,
    const float* __restrict__ meanb, const float* __restrict__ invb,
    const float* __restrict__ ktg, const float* __restrict__ sgbp,
    const float* __restrict__ vtil, const float* __restrict__ bout,
    __hip_bfloat16* __restrict__ catT)
{
    int blk = blockIdx.x;
    int b = blk >> 6;
    long n = (long)(blk & 63) * 64 + (threadIdx.x >> 2);
    int cg = threadIdx.x & 3;
    int t = threadIdx.x;
    __shared__ float kt[NC * C];    // [m][swz(c)] ; swz(c)=(c&63)*4+(c>>6)
    __shared__ float vt[C * NC];    // [swz(c)][m]
    for (int r = 0; r < 16; ++r) {
        int idx = r * 256 + t;
        int m = idx >> 8, c = idx & 255;
        kt[m * 256 + (c & 63) * 4 + (c >> 6)] = ktg[((long)b * NC + m) * C + c];
        int c2 = idx >> 4, m2 = idx & 15;
        vt[((c2 & 63) * 4 + (c2 >> 6)) * 16 + m2] = vtil[((long)b * C + c2) * NC + m2];
    }
    __syncthreads();

    float mu = meanb[(long)b * Nn_ + n];
    float sig = invb[(long)b * Nn_ + n];

    float s[NC];
    #pragma unroll
    for (int m = 0; m < NC; ++m) s[m] = 0.f;
    const __hip_bfloat16* xr = qryTb + ((long)b * Nn_ + n) * C + cg * 64;
    for (int c8 = 0; c8 < 8; ++c8) {
        bf16x8 xv = *(const bf16x8*)(xr + c8 * 8);
        #pragma unroll
        for (int e = 0; e < 8; ++e) {
            float xf = (float)xv[e];
            int ic = c8 * 8 + e;
            #pragma unroll
            for (int m = 0; m < NC; ++m)
                s[m] += xf * kt[m * 256 + ic * 4 + cg];
        }
    }
    #pragma unroll
    for (int m = 0; m < NC; ++m) {
        s[m] += __shfl_xor(s[m], 1);
        s[m] += __shfl_xor(s[m], 2);
        s[m] = sig * s[m] - mu * sig * sgbp[(b * NC + m) * 2] + sgbp[(b * NC + m) * 2 + 1];
    }
    float mx = -1e30f;
    #pragma unroll
    for (int m = 0; m < NC; ++m) mx = fmaxf(mx, s[m]);
    float sum = 0.f;
    #pragma unroll
    for (int m = 0; m < NC; ++m) { s[m] = __expf(s[m] - mx); sum += s[m]; }
    float dn = 1.0f / sum;

    const __hip_bfloat16* qr = qryTb + ((long)b * Nn_ + n) * C + cg * 64;
    __hip_bfloat16* outp = catT + ((long)b * Nn_ + n) * (2 * C) + C + cg * 64;
    for (int c8 = 0; c8 < 8; ++c8) {
        union { ushort4 u; __hip_bfloat16 h[4]; } cv0, cv1;
        #pragma unroll
        for (int e = 0; e < 8; ++e) {
            int ic = c8 * 8 + e;
            int c = cg * 64 + ic;
            float acc = __bfloat162float(qr[ic]) + bout[c];
            float pv = 0.f;
            #pragma unroll
            for (int m = 0; m < NC; ++m)
                pv += vt[(ic * 4 + cg) * 16 + m] * s[m];
            acc += pv * dn;
            if (e < 4) cv0.h[e] = __float2bfloat16(acc);
            else       cv1.h[e - 4] = __float2bfloat16(acc);
        }
        *(ushort4*)(outp + c8 * 8) = cv0.u;
        *(ushort4*)(outp + c8 * 8 + 4) = cv1.u;
    }
}

// ---------------------------------------------------------------------------
// 64x64-tile MFMA bf16 GEMM (high occupancy) for projection GEMMs.
__global__ __launch_bounds__(256) void gemm64(
    const __hip_bfloat16* __restrict__ A,
    const __hip_bfloat16* __restrict__ Bt,
    float* __restrict__ D,
    __hip_bfloat16* __restrict__ Dbf,
    int M, int N, int K, int lda, int ldb, int ldd,
    long batchA, long batchB, long batchD,
    const float* __restrict__ biasRow,
    const float* __restrict__ biasCol, long bcStride,
    const float* __restrict__ resid,
    const __hip_bfloat16* __restrict__ residB, int ldr, long batchR,
    float alpha, int relu)
{
    __shared__ __align__(16) __hip_bfloat16 As[64 * 32];
    __shared__ __align__(16) __hip_bfloat16 Bs[64 * 32];
    int bz = blockIdx.z;
    const __hip_bfloat16* Ab = A + (long)bz * batchA;
    const __hip_bfloat16* Bb = Bt + (long)bz * batchB;
    int m0 = blockIdx.y * 64, n0 = blockIdx.x * 64;
    int tid = threadIdx.x;
    int lane = tid & 63, wave = tid >> 6;
    int wr = wave >> 1, wc = wave & 1;
    int lr = lane & 15, lg = lane >> 4;
    int srow = tid >> 2, ske = (tid & 3) * 8;

    f32x4 acc[2][2];
    #pragma unroll
    for (int i = 0; i < 2; ++i)
        #pragma unroll
        for (int j = 0; j < 2; ++j)
            #pragma unroll
            for (int r = 0; r < 4; ++r) acc[i][j][r] = 0.f;

    for (int k0 = 0; k0 < K; k0 += 32) {
        uint4 va = *(const uint4*)(Ab + (long)(m0 + srow) * lda + k0 + ske);
        uint4 vb = *(const uint4*)(Bb + (long)(n0 + srow) * ldb + k0 + ske);
        ((uint4*)As)[tid] = va;
        ((uint4*)Bs)[tid] = vb;
        __syncthreads();
        bf16x8 af[2], bfr[2];
        #pragma unroll
        for (int i = 0; i < 2; ++i)
            af[i] = *(const bf16x8*)(As + (wr * 32 + i * 16 + lr) * 32 + lg * 8);
        #pragma unroll
        for (int j = 0; j < 2; ++j)
            bfr[j] = *(const bf16x8*)(Bs + (wc * 32 + j * 16 + lr) * 32 + lg * 8);
        #pragma unroll
        for (int i = 0; i < 2; ++i)
            #pragma unroll
            for (int j = 0; j < 2; ++j)
                acc[i][j] = __builtin_amdgcn_mfma_f32_16x16x32_bf16(af[i], bfr[j], acc[i][j], 0, 0, 0);
        __syncthreads();
    }

    int colc = n0 + wc * 32 + lr;
    #pragma unroll
    for (int i = 0; i < 2; ++i) {
        #pragma unroll
        for (int r = 0; r < 4; ++r) {
            int row = m0 + wr * 32 + i * 16 + lg * 4 + r;
            float brv = biasRow ? biasRow[row] : 0.f;
            #pragma unroll
            for (int j = 0; j < 2; ++j) {
                int cc = colc + j * 16;
                float v = acc[i][j][r] * alpha + brv;
                if (biasCol) v += biasCol[bz * bcStride + cc];
                if (resid) v += resid[(long)bz * batchR + (long)row * ldr + cc];
                if (residB) v += __bfloat162float(residB[(long)bz * batchR + (long)row * ldr + cc]);
                if (relu) v = fmaxf(v, 0.f);
                long oa = (long)bz * batchD + (long)row * ldd + cc;
                if (Dbf) Dbf[oa] = __float2bfloat16(v);
                else     D[oa] = v;
            }
        }
    }
}

// ---------------------------------------------------------------------------
__global__ __launch_bounds__(256) void extract_v(
    const __hip_bfloat16* __restrict__ qkvT, __hip_bfloat16* __restrict__ vB)
{
    int b = blockIdx.z;
    int c0 = blockIdx.y * 64, m0 = blockIdx.x * 64;
    __shared__ __hip_bfloat16 tb[64][66];
    int tx = threadIdx.x & 63, tg = threadIdx.x >> 6;
    for (int rr = tg; rr < 64; rr += 4)
        tb[rr][tx] = qkvT[((long)b * Nn_ + m0 + rr) * (3 * C) + 2 * C + c0 + tx];
    __syncthreads();
    for (int rr = tg; rr < 64; rr += 4)
        vB[((long)b * C + c0 + rr) * Nn_ + m0 + tx] = tb[tx][rr];
}

// ---------------------------------------------------------------------------
// Flash attention (round-12 version, best measured: 70us).
__global__ __launch_bounds__(256) void flash_attn(
    const __hip_bfloat16* __restrict__ qkvT,
    const __hip_bfloat16* __restrict__ vB,
    __hip_bfloat16* __restrict__ Opart,   // [B][KVSPLIT][N][256] bf16
    float* __restrict__ lsum)             // [B][KVSPLIT][N]
{
    int qb = blockIdx.x, sp = blockIdx.y, b = blockIdx.z;
    int n0 = qb * 64;
    int tid = threadIdx.x;
    int lane = tid & 63, w = tid >> 6;
    int lr = lane & 15, lg = lane >> 4;

    __shared__ __align__(16) char Ks[32 * 512];
    __shared__ __align__(16) char Vs[128 * 128];
    __shared__ __align__(16) char Pl[32 * 128];

    bf16x8 qf[8];
    {
        const __hip_bfloat16* qp = qkvT + ((long)b * Nn_ + n0 + w * 16 + lr) * (3 * C);
        #pragma unroll
        for (int ks = 0; ks < 8; ++ks)
            qf[ks] = *(const bf16x8*)(qp + ks * 32 + lg * 8);
    }

    const __hip_bfloat16* kbase = qkvT + ((long)b * Nn_) * (3 * C) + C;
    const __hip_bfloat16* vbase = vB + (long)b * C * Nn_;
    int kvBeg = sp * (Nn_ / KVSPLIT);

    int krow[4], kc[4], koff[4], vd[4], vc[4], voff[4];
    #pragma unroll
    for (int ps = 0; ps < 4; ++ps) {
        int id = ps * 256 + tid;
        krow[ps] = id >> 5; kc[ps] = id & 31;
        koff[ps] = krow[ps] * 512 + ((kc[ps] * 16) ^ ((krow[ps] & 7) << 4));
        vd[ps] = id >> 2; vc[ps] = id & 3;
        int vp = vd[ps] >> 1;
        voff[ps] = vp * 128 + ((((vd[ps] & 1) * 64) + vc[ps] * 16) ^ ((vp & 7) << 4));
    }

    f32x4 Oacc[16];
    #pragma unroll
    for (int jd = 0; jd < 16; ++jd)
        #pragma unroll
        for (int r = 0; r < 4; ++r) Oacc[jd][r] = 0.f;
    float l_r[4] = {0.f, 0.f, 0.f, 0.f};

    const int NT = (Nn_ / KVSPLIT) / KVB;   // 16
    for (int t = 0; t < NT; ++t) {
        int kv0 = kvBeg + t * KVB;
        uint4 kr[4], vr[4];
        #pragma unroll
        for (int ps = 0; ps < 4; ++ps) {
            kr[ps] = *(const uint4*)(kbase + (long)(kv0 + krow[ps]) * (3 * C) + kc[ps] * 8);
            vr[ps] = *(const uint4*)(vbase + (long)vd[ps] * Nn_ + kv0 + vc[ps] * 8);
        }
        #pragma unroll
        for (int ps = 0; ps < 4; ++ps) {
            *(uint4*)(Ks + koff[ps]) = kr[ps];
            *(uint4*)(Vs + voff[ps]) = vr[ps];
        }
        __syncthreads();
        // ---- S = Q K^T (log2-domain)
        f32x4 sacc[2];
        #pragma unroll
        for (int j = 0; j < 2; ++j)
            #pragma unroll
            for (int r = 0; r < 4; ++r) sacc[j][r] = 0.f;
        __builtin_amdgcn_s_setprio(1);
        #pragma unroll
        for (int ks = 0; ks < 8; ++ks) {
            #pragma unroll
            for (int j = 0; j < 2; ++j) {
                int row = j * 16 + lr;
                bf16x8 kf = *(const bf16x8*)(Ks + row * 512 +
                            ((ks * 64 + lg * 16) ^ ((row & 7) << 4)));
                sacc[j] = __builtin_amdgcn_mfma_f32_16x16x32_bf16(qf[ks], kf, sacc[j], 0, 0, 0);
            }
        }
        __builtin_amdgcn_s_setprio(0);
        // ---- P = exp2(S) -> Pl
        #pragma unroll
        for (int j = 0; j < 2; ++j)
            #pragma unroll
            for (int r = 0; r < 4; ++r) {
                float p = __builtin_amdgcn_exp2f(sacc[j][r]);
                l_r[r] += p;
                int prow = w * 16 + 4 * lg + r;
                int pp = prow >> 1;
                *(__hip_bfloat16*)(Pl + pp * 128 +
                    ((((prow & 1) * 64) + (j * 16 + lr) * 2) ^ ((pp & 7) << 4))) =
                    __float2bfloat16(p);
            }
        // ---- O += P V^T
        __builtin_amdgcn_s_setprio(1);
        {
            int prow = w * 16 + lr;
            int pp = prow >> 1;
            bf16x8 pf = *(const bf16x8*)(Pl + pp * 128 +
                        ((((prow & 1) * 64) + lg * 16) ^ ((pp & 7) << 4)));
            #pragma unroll
            for (int jd = 0; jd < 16; ++jd) {
                int vrw = jd * 16 + lr;
                int vp = vrw >> 1;
                bf16x8 vf = *(const bf16x8*)(Vs + vp * 128 +
                            ((((vrw & 1) * 64) + lg * 16) ^ ((vp & 7) << 4)));
                Oacc[jd] = __builtin_amdgcn_mfma_f32_16x16x32_bf16(pf, vf, Oacc[jd], 0, 0, 0);
            }
        }
        __builtin_amdgcn_s_setprio(0);
        __syncthreads();
    }

    #pragma unroll
    for (int r = 0; r < 4; ++r) {
        float v = l_r[r];
        #pragma unroll
        for (int off = 1; off <= 8; off <<= 1)
            v += __shfl_xor(v, off);
        l_r[r] = v;
    }

    __hip_bfloat16* Op = Opart + (((long)b * KVSPLIT + sp) * Nn_ + n0) * 256;
    #pragma unroll
    for (int jd = 0; jd < 16; ++jd)
        #pragma unroll
        for (int r = 0; r < 4; ++r) {
            int row = w * 16 + lg * 4 + r;
            Op[(long)row * 256 + jd * 16 + lr] = __float2bfloat16(Oacc[jd][r]);
        }
    if (lr == 0) {
        float* lp = lsum + ((long)b * KVSPLIT + sp) * Nn_ + n0;
        #pragma unroll
        for (int r = 0; r < 4; ++r)
            lp[w * 16 + lg * 4 + r] = l_r[r];
    }
}

// ---------------------------------------------------------------------------
__global__ __launch_bounds__(256) void merge_flash(
    const __hip_bfloat16* __restrict__ Opart, const float* __restrict__ lsum,
    __hip_bfloat16* __restrict__ refsT)
{
    long gi = (long)blockIdx.x * 256 + threadIdx.x;
    long row = gi >> 6;
    int c4 = (int)(gi & 63) * 4;
    long b = row / Nn_, n = row % Nn_;
    float l = 0.f;
    float o0 = 0.f, o1 = 0.f, o2 = 0.f, o3 = 0.f;
    #pragma unroll
    for (int sp = 0; sp < KVSPLIT; ++sp) {
        long rr = (b * KVSPLIT + sp) * Nn_ + n;
        l += lsum[rr];
        union { ushort4 u; __hip_bfloat16 h[4]; } rv;
        rv.u = *(const ushort4*)(Opart + rr * 256 + c4);
        o0 += __bfloat162float(rv.h[0]);
        o1 += __bfloat162float(rv.h[1]);
        o2 += __bfloat162float(rv.h[2]);
        o3 += __bfloat162float(rv.h[3]);
    }
    float dn = 1.0f / l;
    union { ushort4 u; __hip_bfloat16 h[4]; } cv;
    cv.h[0] = __float2bfloat16(o0 * dn);
    cv.h[1] = __float2bfloat16(o1 * dn);
    cv.h[2] = __float2bfloat16(o2 * dn);
    cv.h[3] = __float2bfloat16(o3 * dn);
    *(ushort4*)(refsT + (b * Nn_ + n) * 256 + c4) = cv.u;
}

// ---------------------------------------------------------------------------
// Implicit-GEMM 3x3 conv, 9-way tap-split (1152 blocks). partials bf16.
__global__ __launch_bounds__(256) void conv3x3_gemm(
    const __hip_bfloat16* __restrict__ catT,
    const __hip_bfloat16* __restrict__ Wtap,
    __hip_bfloat16* __restrict__ partials)
{
    __shared__ __align__(16) __hip_bfloat16 As[128 * 32];
    __shared__ __align__(16) __hip_bfloat16 Bs[128 * 32];
    int z = blockIdx.z;
    int b = z / 9, sp = z % 9;
    int dh = sp / 3 - 1, dw = sp % 3 - 1;
    int o0 = blockIdx.x * 128, m0 = blockIdx.y * 128;
    int tid = threadIdx.x;
    int lane = tid & 63, wave = tid >> 6;
    int wr = wave >> 1, wc = wave & 1;
    int lr = lane & 15, lg = lane >> 4;
    const __hip_bfloat16* cb = catT + (long)b * Nn_ * (2 * C);
    const __hip_bfloat16* wt = Wtap + (long)sp * C * (2 * C);

    f32x4 acc[4][4];
    #pragma unroll
    for (int i = 0; i < 4; ++i)
        #pragma unroll
        for (int j = 0; j < 4; ++j)
            #pragma unroll
            for (int r = 0; r < 4; ++r) acc[i][j][r] = 0.f;

    for (int k0 = 0; k0 < 2 * C; k0 += 32) {
        #pragma unroll
        for (int q = 0; q < 2; ++q) {
            int idx = q * 256 + tid;
            int row = idx >> 2;
            int ke = (idx & 3) * 8;
            int gm = m0 + row;
            int h = (gm >> 6) + dh, w2 = (gm & 63) + dw;
            uint4 va = {0, 0, 0, 0};
            if ((unsigned)h < 64u && (unsigned)w2 < 64u)
                va = *(const uint4*)(cb + ((long)((h << 6) + w2)) * (2 * C) + k0 + ke);
            ((uint4*)As)[idx] = va;
            ((uint4*)Bs)[idx] = *(const uint4*)(wt + (long)(o0 + row) * (2 * C) + k0 + ke);
        }
        __syncthreads();
        bf16x8 af[4], bfr[4];
        #pragma unroll
        for (int i = 0; i < 4; ++i)
            af[i] = *(const bf16x8*)(As + (wr * 64 + i * 16 + lr) * 32 + lg * 8);
        #pragma unroll
        for (int j = 0; j < 4; ++j)
            bfr[j] = *(const bf16x8*)(Bs + (wc * 64 + j * 16 + lr) * 32 + lg * 8);
        #pragma unroll
        for (int i = 0; i < 4; ++i)
            #pragma unroll
            for (int j = 0; j < 4; ++j)
                acc[i][j] = __builtin_amdgcn_mfma_f32_16x16x32_bf16(af[i], bfr[j], acc[i][j], 0, 0, 0);
        __syncthreads();
    }

    __hip_bfloat16* Dp = partials + ((long)(b * 9 + sp) * Nn_ + m0) * 256;
    #pragma unroll
    for (int i = 0; i < 4; ++i)
        #pragma unroll
        for (int r = 0; r < 4; ++r) {
            int row = wr * 64 + i * 16 + lg * 4 + r;
            #pragma unroll
            for (int j = 0; j < 4; ++j)
                Dp[(long)row * 256 + o0 + wc * 64 + j * 16 + lr] =
                    __float2bfloat16(acc[i][j][r]);
        }
}

// ---------------------------------------------------------------------------
// Sum 9 bf16 tap-partials -> y1T bf16 with relu (both batches, one launch).
__global__ __launch_bounds__(256) void reduce_partials(
    const __hip_bfloat16* __restrict__ part, long perBatch, long partStride,
    __hip_bfloat16* __restrict__ out, long nPerBatch)
{
    long gi = ((long)blockIdx.x * 256 + threadIdx.x) * 4;
    long total = (long)Bb_ * nPerBatch;
    if (gi >= total) return;
    long b = gi / nPerBatch;
    long i = gi % nPerBatch;
    const __hip_bfloat16* pb = part + b * perBatch;
    float a[4] = {0.f, 0.f, 0.f, 0.f};
    #pragma unroll
    for (int sp = 0; sp < 9; ++sp) {
        union { ushort4 u; __hip_bfloat16 h[4]; } rv;
        rv.u = *(const ushort4*)(pb + (long)sp * partStride + i);
        #pragma unroll
        for (int k = 0; k < 4; ++k) a[k] += __bfloat162float(rv.h[k]);
    }
    union { ushort4 u; __hip_bfloat16 h[4]; } cv;
    #pragma unroll
    for (int k = 0; k < 4; ++k)
        cv.h[k] = __float2bfloat16(fmaxf(a[k], 0.f));
    *(ushort4*)(out + b * nPerBatch + i) = cv.u;
}

// ---------------------------------------------------------------------------
extern "C" void kernel_launch(void* const* d_in, const int* in_sizes, int n_in,
                              void* d_out, int out_size, void* d_ws, size_t ws_size,
                              hipStream_t stream)
{
    const float* qry   = (const float*)d_in[0];
    const float* arch  = (const float*)d_in[1];
    const float* ctx   = (const float*)d_in[2];
    const float* ln1_g = (const float*)d_in[3];
    const float* ln1_b = (const float*)d_in[4];
    const float* Wqkv  = (const float*)d_in[5];
    const float* bqkv  = (const float*)d_in[6];
    const float* Wproj = (const float*)d_in[7];
    const float* bproj = (const float*)d_in[8];
    const float* Wg    = (const float*)d_in[9];
    const float* bg    = (const float*)d_in[10];
    const float* ln2_g = (const float*)d_in[11];
    const float* ln2_b = (const float*)d_in[12];
    const float* Wq    = (const float*)d_in[13];
    const float* bq    = (const float*)d_in[14];
    const float* Wkv   = (const float*)d_in[15];
    const float* bkv   = (const float*)d_in[16];
    const float* Wout  = (const float*)d_in[17];
    const float* bout  = (const float*)d_in[18];
    const float* Wf1   = (const float*)d_in[19];
    const float* Wf2   = (const float*)d_in[20];
    const float* bf2   = (const float*)d_in[21];
    float* out = (float*)d_out;

    const long CN = (long)C * Nn_;
    const long MN = (long)Nn_ * C;
    char* ws = (char*)d_ws;
    size_t off = 0;
    auto alloc = [&](size_t bytes) -> char* {
        char* p = ws + off;
        off += (bytes + 255) & ~size_t(255);
        return p;
    };
    float* lbuf     = (float*)alloc((long)Bb_ * KVSPLIT * Nn_ * 4);
    float* gate     = (float*)alloc(Bb_ * C * 4);
    float* biasCol  = (float*)alloc((long)Bb_ * 3 * C * 4);
    float* ktg      = (float*)alloc((long)Bb_ * NC * C * 4);
    float* sgbp     = (float*)alloc((long)Bb_ * NC * 2 * 4);
    float* vtil     = (float*)alloc((long)Bb_ * C * NC * 4);
    float* meanb    = (float*)alloc((long)Bb_ * Nn_ * 4);
    float* invb     = (float*)alloc((long)Bb_ * Nn_ * 4);
    __hip_bfloat16* Opart = (__hip_bfloat16*)alloc((long)Bb_ * KVSPLIT * MN * 2);
    __hip_bfloat16* convPart = (__hip_bfloat16*)alloc((long)Bb_ * 9 * MN * 2);
    __hip_bfloat16* qryTb = (__hip_bfloat16*)alloc(Bb_ * MN * 2);
    __hip_bfloat16* x1T   = (__hip_bfloat16*)alloc(Bb_ * MN * 2);
    __hip_bfloat16* qkvT  = (__hip_bfloat16*)alloc((long)Bb_ * Nn_ * 3 * C * 2);
    __hip_bfloat16* vB    = (__hip_bfloat16*)alloc(Bb_ * CN * 2);
    __hip_bfloat16* refsT = (__hip_bfloat16*)alloc(Bb_ * MN * 2);
    __hip_bfloat16* catT  = (__hip_bfloat16*)alloc((long)Bb_ * Nn_ * 2 * C * 2);
    __hip_bfloat16* y1T   = (__hip_bfloat16*)alloc(Bb_ * MN * 2);
    __hip_bfloat16* WqkvG = (__hip_bfloat16*)alloc((long)Bb_ * 3 * C * C * 2);
    __hip_bfloat16* Wprojb= (__hip_bfloat16*)alloc((long)C * C * 2);
    __hip_bfloat16* Wf2b  = (__hip_bfloat16*)alloc((long)C * C * 2);
    __hip_bfloat16* Wtap  = (__hip_bfloat16*)alloc((long)9 * C * 2 * C * 2);

    // 1. layernorm (ln1 only; ln2 folded) + bf16 qry transpose + mean/inv
    lnT_kernel<<<Bb_ * (Nn_ / 64), 256, 0, stream>>>(
        qry, ln1_g, ln1_b, x1T, qryTb, meanb, invb);

    // 2. gate + weight prep + cross prep (LN2 folded)
    gate_kernel<<<Bb_, 256, 0, stream>>>(arch, Wg, bg, gate);
    build_wqkv<<<(Bb_ * 3 * C * C + 255) / 256, 256, 0, stream>>>(Wqkv, bqkv, gate, WqkvG, biasCol);
    {
        long total = (long)C * C * 2 + 9l * C * 2 * C;
        cast_all<<<(int)((total + 255) / 256), 256, 0, stream>>>(
            Wproj, Wf2, Wf1, Wprojb, Wf2b, Wtap);
    }
    cross_prep<<<Bb_ * NC, 256, 0, stream>>>(
        ctx, Wkv, bkv, Wq, bq, Wout, ln2_g, ln2_b, ktg, sgbp, vtil);

    // 3. qkvT = x1T @ WqkvG^T + biasCol  -> bf16 [B][N][768]  (64x64 tiles)
    gemm64<<<dim3(3 * C / 64, Nn_ / 64, Bb_), 256, 0, stream>>>(
        x1T, WqkvG, nullptr, qkvT, Nn_, 3 * C, C, C, C, 3 * C,
        MN, (long)3 * C * C, (long)Nn_ * 3 * C,
        nullptr, biasCol, 3 * C, nullptr, nullptr, 0, 0, 1.0f, 0);

    // 4. v -> vB [B][C][N]
    extract_v<<<dim3(Nn_ / 64, C / 64, Bb_), 256, 0, stream>>>(qkvT, vB);

    // 5. flash attention + merge -> refsT bf16 [B][N][C]
    flash_attn<<<dim3(Nn_ / 64, KVSPLIT, Bb_), 256, 0, stream>>>(qkvT, vB, Opart, lbuf);
    merge_flash<<<(int)((long)Bb_ * Nn_ * 64 / 256), 256, 0, stream>>>(Opart, lbuf, refsT);

    // 6. catT[:, :256] = qryTb + refsT @ Wproj^T + bproj  (64x64 tiles)
    gemm64<<<dim3(C / 64, Nn_ / 64, Bb_), 256, 0, stream>>>(
        refsT, Wprojb, nullptr, catT, Nn_, C, C, C, C, 2 * C,
        MN, 0, (long)Nn_ * 2 * C,
        nullptr, bproj, 0, nullptr, qryTb, C, MN, 1.0f, 0);

    // 7. catT[:, 256:] = fused cross attention (LN2 folded)
    cross_fused<<<Bb_ * (Nn_ / 64), 256, 0, stream>>>(
        qryTb, meanb, invb, ktg, sgbp, vtil, bout, catT);

    // 8. implicit conv3x3 (9-way tap-split) + fused 2-batch reduce(relu)
    conv3x3_gemm<<<dim3(2, 32, Bb_ * 9), 256, 0, stream>>>(catT, Wtap, convPart);
    reduce_partials<<<(int)((long)Bb_ * MN / 1024), 256, 0, stream>>>(
        convPart, 9 * MN, MN, y1T, MN);

    // 9. out = qry + Wf2 @ y1 + bf2   (fp32 [B][C][N])  (64x64 tiles)
    gemm64<<<dim3(Nn_ / 64, C / 64, Bb_), 256, 0, stream>>>(
        Wf2b, y1T, out, nullptr, C, Nn_, C, C, C, Nn_,
        0, MN, CN,
        bf2, nullptr, 0, qry, nullptr, Nn_, CN, 1.0f, 0);
}

// Round 18
// 210.818 us; speedup vs baseline: 1.5045x; 1.0347x over previous
//
#include <hip/hip_runtime.h>
#include <hip/hip_bf16.h>

#define C 256
#define HID 128
#define Bb_ 2
#define Hh 64
#define Ww 64
#define Nn_ 4096
#define NP 16
#define NC 16
#define KVSPLIT 8
#define KVB 32
#define QKLD (2 * C)   // qkT row stride (q:0..255, k:256..511)

typedef __bf16 bf16x8 __attribute__((ext_vector_type(8)));
typedef float f32x4 __attribute__((ext_vector_type(4)));

// ---------------------------------------------------------------------------
// Coalesced tiled LayerNorm -> x1T bf16 [B][N][C], qryT bf16, mean/inv fp32.
__global__ __launch_bounds__(256) void lnT_kernel(
    const float* __restrict__ x,
    const float* __restrict__ g1, const float* __restrict__ b1,
    __hip_bfloat16* __restrict__ x1T, __hip_bfloat16* __restrict__ qryTb,
    float* __restrict__ meanb, float* __restrict__ invb)
{
    int blk = blockIdx.x;
    int b = blk >> 6;
    int n0 = (blk & 63) << 6;
    int t = threadIdx.x;
    __shared__ __hip_bfloat16 xs[64][258];
    __shared__ float rs4[4][64], rq4[4][64], mean[64], inv[64];
    int j = t & 63, cg = t >> 6;
    float s = 0.f, q = 0.f;
    for (int it = 0; it < 64; ++it) {
        int c = it * 4 + cg;
        float v = x[((long)b * C + c) * Nn_ + n0 + j];
        xs[j][c] = __float2bfloat16(v);
        s += v; q += v * v;
    }
    rs4[cg][j] = s; rq4[cg][j] = q;
    __syncthreads();
    if (t < 64) {
        float S = rs4[0][t] + rs4[1][t] + rs4[2][t] + rs4[3][t];
        float Q = rq4[0][t] + rq4[1][t] + rq4[2][t] + rq4[3][t];
        float m = S * (1.0f / C);
        float var = Q * (1.0f / C) - m * m;
        mean[t] = m; inv[t] = rsqrtf(var + 1e-5f);
        meanb[(long)b * Nn_ + n0 + t] = m;
        invb[(long)b * Nn_ + n0 + t] = inv[t];
    }
    __syncthreads();
    float G1 = g1[t], B1 = b1[t];
    for (int j2 = 0; j2 < 64; ++j2) {
        float v = __bfloat162float(xs[j2][t]);
        float xn = (v - mean[j2]) * inv[j2];
        long o = ((long)b * Nn_ + n0 + j2) * C + t;
        x1T[o] = __float2bfloat16(xn * G1 + B1);
        qryTb[o] = xs[j2][t];
    }
}

// ---------------------------------------------------------------------------
__global__ __launch_bounds__(256) void gate_kernel(
    const float* __restrict__ arch, const float* __restrict__ Wg,
    const float* __restrict__ bg, float* __restrict__ gate)
{
    int b = blockIdx.x;
    int o = threadIdx.x;
    __shared__ float guide[C];
    float s = 0.f;
    for (int p = 0; p < NP; ++p) s += arch[(long)b * NP * C + (long)p * C + o];
    guide[o] = s * (1.0f / NP);
    __syncthreads();
    float acc = bg[o];
    for (int cc = 0; cc < C; ++cc) acc += guide[cc] * Wg[(long)o * C + cc];
    gate[b * C + o] = 1.0f / (1.0f + __expf(-acc));
}

// ---------------------------------------------------------------------------
#define QSCALE 0.09016844005429271f   // log2(e)/16
__global__ __launch_bounds__(256) void build_wqkv(
    const float* __restrict__ Wqkv, const float* __restrict__ bqkv,
    const float* __restrict__ gate,
    __hip_bfloat16* __restrict__ WqkvG, float* __restrict__ biasCol)
{
    long i = (long)blockIdx.x * 256 + threadIdx.x;
    long total = (long)Bb_ * 3 * C * C;
    if (i < total) {
        long b = i / (3 * C * C);
        long rem = i % (3 * C * C);
        int o = (int)(rem / C);
        float v = Wqkv[rem];
        if (o < C) v *= QSCALE;
        else if (o < 2 * C) v *= gate[b * C + (o - C)];
        WqkvG[i] = __float2bfloat16(v);
    }
    if (i < (long)Bb_ * 3 * C) {
        long b = i / (3 * C);
        int o = (int)(i % (3 * C));
        float v = bqkv[o];
        if (o < C) v *= QSCALE;
        else if (o < 2 * C) v *= gate[b * C + (o - C)];
        biasCol[i] = v;
    }
}

// ---------------------------------------------------------------------------
// Cast Wproj, Wf2 to bf16 and build Wtap [9][O][512] from Wf1.
__global__ __launch_bounds__(256) void cast_all(
    const float* __restrict__ Wproj, const float* __restrict__ Wf2,
    const float* __restrict__ Wf1,
    __hip_bfloat16* __restrict__ Wprojb, __hip_bfloat16* __restrict__ Wf2b,
    __hip_bfloat16* __restrict__ Wtap)
{
    long i = (long)blockIdx.x * 256 + threadIdx.x;
    const long nP = (long)C * C;
    const long nT = 9l * C * 2 * C;
    if (i < nP) { Wprojb[i] = __float2bfloat16(Wproj[i]); return; }
    i -= nP;
    if (i < nP) { Wf2b[i] = __float2bfloat16(Wf2[i]); return; }
    i -= nP;
    if (i < nT) {
        int tap = (int)(i / (C * 2 * C));
        long rem = i % (C * 2 * C);
        int o = (int)(rem / (2 * C)), ic = (int)(rem % (2 * C));
        Wtap[i] = __float2bfloat16(Wf1[((long)o * 2 * C + ic) * 9 + tap]);
    }
}

// ---------------------------------------------------------------------------
// Cross-attention algebraic prep with LN2 folded.
__global__ __launch_bounds__(256) void cross_prep(
    const float* __restrict__ ctx, const float* __restrict__ Wkv,
    const float* __restrict__ bkv, const float* __restrict__ Wq,
    const float* __restrict__ bq, const float* __restrict__ Wout,
    const float* __restrict__ g2, const float* __restrict__ b2,
    float* __restrict__ ktg,       // [B][NC][C]
    float* __restrict__ sgbp,      // [B][NC][2]
    float* __restrict__ vtil)      // [B][C][NC]
{
    int b = blockIdx.x >> 4, m = blockIdx.x & 15;
    int t = threadIdx.x;
    __shared__ float cs[C], kl[C], red[256];
    cs[t] = ctx[((long)b * NC + m) * C + t];
    __syncthreads();
    float acc = bkv[t];
    for (int c = 0; c < C; ++c) acc += cs[c] * Wkv[(long)t * C + c];
    kl[t] = acc;
    __syncthreads();
    const float scc = 0.08838834764831845f;  // 1/sqrt(128)
    float kt = 0.f;
    for (int h = 0; h < HID; ++h) kt += kl[h] * Wq[(long)h * C + t];
    kt *= scc;
    float G2 = g2[t], B2 = b2[t];
    ktg[((long)b * NC + m) * C + t] = kt * G2;
    float vt = 0.f;
    for (int h = 0; h < HID; ++h) vt += kl[HID + h] * Wout[(long)t * HID + h];
    vtil[((long)b * C + t) * NC + m] = vt;
    red[t] = kt * G2;
    __syncthreads();
    for (int s = 128; s > 0; s >>= 1) {
        if (t < s) red[t] += red[t + s];
        __syncthreads();
    }
    float sg = red[0];
    __syncthreads();
    red[t] = kt * B2 + ((t < 128) ? scc * bq[t] * kl[t] : 0.f);
    __syncthreads();
    for (int s = 128; s > 0; s >>= 1) {
        if (t < s) red[t] += red[t + s];
        __syncthreads();
    }
    if (t == 0) {
        sgbp[(b * NC + m) * 2] = sg;
        sgbp[(b * NC + m) * 2 + 1] = red[0];
    }
}

// ---------------------------------------------------------------------------
// Fused cross attention (LN2 folded) -> catT right half.
__global__ __launch_bounds__(256) void cross_fused(
    const __hip_bfloat16* __restrict__ qryTb,
    const float* __restrict__ meanb, const float* __restrict__ invb,
    const float* __restrict__ ktg, const float* __restrict__ sgbp,
    const float* __restrict__ vtil, const float* __restrict__ bout,
    __hip_bfloat16* __restrict__ catT)
{
    int blk = blockIdx.x;
    int b = blk >> 6;
    long n = (long)(blk & 63) * 64 + (threadIdx.x >> 2);
    int cg = threadIdx.x & 3;
    int t = threadIdx.x;
    __shared__ float kt[NC * C];
    __shared__ float vt[C * NC];
    for (int r = 0; r < 16; ++r) {
        int idx = r * 256 + t;
        int m = idx >> 8, c = idx & 255;
        kt[m * 256 + (c & 63) * 4 + (c >> 6)] = ktg[((long)b * NC + m) * C + c];
        int c2 = idx >> 4, m2 = idx & 15;
        vt[((c2 & 63) * 4 + (c2 >> 6)) * 16 + m2] = vtil[((long)b * C + c2) * NC + m2];
    }
    __syncthreads();

    float mu = meanb[(long)b * Nn_ + n];
    float sig = invb[(long)b * Nn_ + n];

    float s[NC];
    #pragma unroll
    for (int m = 0; m < NC; ++m) s[m] = 0.f;
    const __hip_bfloat16* xr = qryTb + ((long)b * Nn_ + n) * C + cg * 64;
    for (int c8 = 0; c8 < 8; ++c8) {
        bf16x8 xv = *(const bf16x8*)(xr + c8 * 8);
        #pragma unroll
        for (int e = 0; e < 8; ++e) {
            float xf = (float)xv[e];
            int ic = c8 * 8 + e;
            #pragma unroll
            for (int m = 0; m < NC; ++m)
                s[m] += xf * kt[m * 256 + ic * 4 + cg];
        }
    }
    #pragma unroll
    for (int m = 0; m < NC; ++m) {
        s[m] += __shfl_xor(s[m], 1);
        s[m] += __shfl_xor(s[m], 2);
        s[m] = sig * s[m] - mu * sig * sgbp[(b * NC + m) * 2] + sgbp[(b * NC + m) * 2 + 1];
    }
    float mx = -1e30f;
    #pragma unroll
    for (int m = 0; m < NC; ++m) mx = fmaxf(mx, s[m]);
    float sum = 0.f;
    #pragma unroll
    for (int m = 0; m < NC; ++m) { s[m] = __expf(s[m] - mx); sum += s[m]; }
    float dn = 1.0f / sum;

    const __hip_bfloat16* qr = qryTb + ((long)b * Nn_ + n) * C + cg * 64;
    __hip_bfloat16* outp = catT + ((long)b * Nn_ + n) * (2 * C) + C + cg * 64;
    for (int c8 = 0; c8 < 8; ++c8) {
        union { ushort4 u; __hip_bfloat16 h[4]; } cv0, cv1;
        #pragma unroll
        for (int e = 0; e < 8; ++e) {
            int ic = c8 * 8 + e;
            int c = cg * 64 + ic;
            float acc = __bfloat162float(qr[ic]) + bout[c];
            float pv = 0.f;
            #pragma unroll
            for (int m = 0; m < NC; ++m)
                pv += vt[(ic * 4 + cg) * 16 + m] * s[m];
            acc += pv * dn;
            if (e < 4) cv0.h[e] = __float2bfloat16(acc);
            else       cv1.h[e - 4] = __float2bfloat16(acc);
        }
        *(ushort4*)(outp + c8 * 8) = cv0.u;
        *(ushort4*)(outp + c8 * 8 + 4) = cv1.u;
    }
}

// ---------------------------------------------------------------------------
// 64x64-tile MFMA bf16 GEMM (high occupancy) for projection GEMMs.
__global__ __launch_bounds__(256) void gemm64(
    const __hip_bfloat16* __restrict__ A,
    const __hip_bfloat16* __restrict__ Bt,
    float* __restrict__ D,
    __hip_bfloat16* __restrict__ Dbf,
    int M, int N, int K, int lda, int ldb, int ldd,
    long batchA, long batchB, long batchD,
    const float* __restrict__ biasRow,
    const float* __restrict__ biasCol, long bcStride,
    const float* __restrict__ resid,
    const __hip_bfloat16* __restrict__ residB, int ldr, long batchR,
    float alpha, int relu)
{
    __shared__ __align__(16) __hip_bfloat16 As[64 * 32];
    __shared__ __align__(16) __hip_bfloat16 Bs[64 * 32];
    int bz = blockIdx.z;
    const __hip_bfloat16* Ab = A + (long)bz * batchA;
    const __hip_bfloat16* Bb = Bt + (long)bz * batchB;
    int m0 = blockIdx.y * 64, n0 = blockIdx.x * 64;
    int tid = threadIdx.x;
    int lane = tid & 63, wave = tid >> 6;
    int wr = wave >> 1, wc = wave & 1;
    int lr = lane & 15, lg = lane >> 4;
    int srow = tid >> 2, ske = (tid & 3) * 8;

    f32x4 acc[2][2];
    #pragma unroll
    for (int i = 0; i < 2; ++i)
        #pragma unroll
        for (int j = 0; j < 2; ++j)
            #pragma unroll
            for (int r = 0; r < 4; ++r) acc[i][j][r] = 0.f;

    for (int k0 = 0; k0 < K; k0 += 32) {
        uint4 va = *(const uint4*)(Ab + (long)(m0 + srow) * lda + k0 + ske);
        uint4 vb = *(const uint4*)(Bb + (long)(n0 + srow) * ldb + k0 + ske);
        ((uint4*)As)[tid] = va;
        ((uint4*)Bs)[tid] = vb;
        __syncthreads();
        bf16x8 af[2], bfr[2];
        #pragma unroll
        for (int i = 0; i < 2; ++i)
            af[i] = *(const bf16x8*)(As + (wr * 32 + i * 16 + lr) * 32 + lg * 8);
        #pragma unroll
        for (int j = 0; j < 2; ++j)
            bfr[j] = *(const bf16x8*)(Bs + (wc * 32 + j * 16 + lr) * 32 + lg * 8);
        #pragma unroll
        for (int i = 0; i < 2; ++i)
            #pragma unroll
            for (int j = 0; j < 2; ++j)
                acc[i][j] = __builtin_amdgcn_mfma_f32_16x16x32_bf16(af[i], bfr[j], acc[i][j], 0, 0, 0);
        __syncthreads();
    }

    int colc = n0 + wc * 32 + lr;
    #pragma unroll
    for (int i = 0; i < 2; ++i) {
        #pragma unroll
        for (int r = 0; r < 4; ++r) {
            int row = m0 + wr * 32 + i * 16 + lg * 4 + r;
            float brv = biasRow ? biasRow[row] : 0.f;
            #pragma unroll
            for (int j = 0; j < 2; ++j) {
                int cc = colc + j * 16;
                float v = acc[i][j][r] * alpha + brv;
                if (biasCol) v += biasCol[bz * bcStride + cc];
                if (resid) v += resid[(long)bz * batchR + (long)row * ldr + cc];
                if (residB) v += __bfloat162float(residB[(long)bz * batchR + (long)row * ldr + cc]);
                if (relu) v = fmaxf(v, 0.f);
                long oa = (long)bz * batchD + (long)row * ldd + cc;
                if (Dbf) Dbf[oa] = __float2bfloat16(v);
                else     D[oa] = v;
            }
        }
    }
}

// ---------------------------------------------------------------------------
// qkv GEMM with fused v-transpose: cols 0..511 -> qkT [N][512]; cols 512..767
// transposed in-LDS -> vB [C][N] (coalesced 128B rows). Kills extract_v.
__global__ __launch_bounds__(256) void gemm64_qkv(
    const __hip_bfloat16* __restrict__ A,      // x1T [B][N][C]
    const __hip_bfloat16* __restrict__ Bt,     // WqkvG [B][768][C]
    const float* __restrict__ biasCol,         // [B][768]
    __hip_bfloat16* __restrict__ qkT,          // [B][N][512]
    __hip_bfloat16* __restrict__ vB)           // [B][C][N]
{
    __shared__ __align__(16) __hip_bfloat16 As[64 * 32];
    __shared__ __align__(16) __hip_bfloat16 Bs[64 * 32];
    __shared__ __hip_bfloat16 tb[64][66];
    int bz = blockIdx.z;
    const __hip_bfloat16* Ab = A + (long)bz * Nn_ * C;
    const __hip_bfloat16* Bb = Bt + (long)bz * 3 * C * C;
    int m0 = blockIdx.y * 64, n0 = blockIdx.x * 64;
    int tid = threadIdx.x;
    int lane = tid & 63, wave = tid >> 6;
    int wr = wave >> 1, wc = wave & 1;
    int lr = lane & 15, lg = lane >> 4;
    int srow = tid >> 2, ske = (tid & 3) * 8;

    f32x4 acc[2][2];
    #pragma unroll
    for (int i = 0; i < 2; ++i)
        #pragma unroll
        for (int j = 0; j < 2; ++j)
            #pragma unroll
            for (int r = 0; r < 4; ++r) acc[i][j][r] = 0.f;

    for (int k0 = 0; k0 < C; k0 += 32) {
        uint4 va = *(const uint4*)(Ab + (long)(m0 + srow) * C + k0 + ske);
        uint4 vb = *(const uint4*)(Bb + (long)(n0 + srow) * C + k0 + ske);
        ((uint4*)As)[tid] = va;
        ((uint4*)Bs)[tid] = vb;
        __syncthreads();
        bf16x8 af[2], bfr[2];
        #pragma unroll
        for (int i = 0; i < 2; ++i)
            af[i] = *(const bf16x8*)(As + (wr * 32 + i * 16 + lr) * 32 + lg * 8);
        #pragma unroll
        for (int j = 0; j < 2; ++j)
            bfr[j] = *(const bf16x8*)(Bs + (wc * 32 + j * 16 + lr) * 32 + lg * 8);
        #pragma unroll
        for (int i = 0; i < 2; ++i)
            #pragma unroll
            for (int j = 0; j < 2; ++j)
                acc[i][j] = __builtin_amdgcn_mfma_f32_16x16x32_bf16(af[i], bfr[j], acc[i][j], 0, 0, 0);
        __syncthreads();
    }

    if (n0 < 2 * C) {
        // q/k path: direct write, stride QKLD
        #pragma unroll
        for (int i = 0; i < 2; ++i)
            #pragma unroll
            for (int r = 0; r < 4; ++r) {
                int row = m0 + wr * 32 + i * 16 + lg * 4 + r;
                #pragma unroll
                for (int j = 0; j < 2; ++j) {
                    int cc = n0 + wc * 32 + lr + j * 16;
                    float v = acc[i][j][r] + biasCol[bz * 3 * C + cc];
                    qkT[((long)bz * Nn_ + row) * QKLD + cc] = __float2bfloat16(v);
                }
            }
    } else {
        // v path: transpose via LDS, write vB coalesced
        #pragma unroll
        for (int i = 0; i < 2; ++i)
            #pragma unroll
            for (int r = 0; r < 4; ++r) {
                int rowl = wr * 32 + i * 16 + lg * 4 + r;
                #pragma unroll
                for (int j = 0; j < 2; ++j) {
                    int coll = wc * 32 + lr + j * 16;
                    float v = acc[i][j][r] + biasCol[bz * 3 * C + n0 + coll];
                    tb[coll][rowl] = __float2bfloat16(v);
                }
            }
        __syncthreads();
        int c0 = n0 - 2 * C;
        #pragma unroll
        for (int it = 0; it < 8; ++it) {
            int rowl = it * 8 + (tid >> 5);
            int cp = tid & 31;
            __hip_bfloat16* dst = vB + ((long)bz * C + c0 + rowl) * Nn_ + m0 + cp * 2;
            dst[0] = tb[rowl][cp * 2];
            dst[1] = tb[rowl][cp * 2 + 1];
        }
    }
}

// ---------------------------------------------------------------------------
// Flash attention (round-12 structure; q/k now from qkT stride 512).
__global__ __launch_bounds__(256) void flash_attn(
    const __hip_bfloat16* __restrict__ qkT,
    const __hip_bfloat16* __restrict__ vB,
    __hip_bfloat16* __restrict__ Opart,   // [B][KVSPLIT][N][256] bf16
    float* __restrict__ lsum)             // [B][KVSPLIT][N]
{
    int qb = blockIdx.x, sp = blockIdx.y, b = blockIdx.z;
    int n0 = qb * 64;
    int tid = threadIdx.x;
    int lane = tid & 63, w = tid >> 6;
    int lr = lane & 15, lg = lane >> 4;

    __shared__ __align__(16) char Ks[32 * 512];
    __shared__ __align__(16) char Vs[128 * 128];
    __shared__ __align__(16) char Pl[32 * 128];

    bf16x8 qf[8];
    {
        const __hip_bfloat16* qp = qkT + ((long)b * Nn_ + n0 + w * 16 + lr) * QKLD;
        #pragma unroll
        for (int ks = 0; ks < 8; ++ks)
            qf[ks] = *(const bf16x8*)(qp + ks * 32 + lg * 8);
    }

    const __hip_bfloat16* kbase = qkT + ((long)b * Nn_) * QKLD + C;
    const __hip_bfloat16* vbase = vB + (long)b * C * Nn_;
    int kvBeg = sp * (Nn_ / KVSPLIT);

    int krow[4], kc[4], koff[4], vd[4], vc[4], voff[4];
    #pragma unroll
    for (int ps = 0; ps < 4; ++ps) {
        int id = ps * 256 + tid;
        krow[ps] = id >> 5; kc[ps] = id & 31;
        koff[ps] = krow[ps] * 512 + ((kc[ps] * 16) ^ ((krow[ps] & 7) << 4));
        vd[ps] = id >> 2; vc[ps] = id & 3;
        int vp = vd[ps] >> 1;
        voff[ps] = vp * 128 + ((((vd[ps] & 1) * 64) + vc[ps] * 16) ^ ((vp & 7) << 4));
    }

    f32x4 Oacc[16];
    #pragma unroll
    for (int jd = 0; jd < 16; ++jd)
        #pragma unroll
        for (int r = 0; r < 4; ++r) Oacc[jd][r] = 0.f;
    float l_r[4] = {0.f, 0.f, 0.f, 0.f};

    const int NT = (Nn_ / KVSPLIT) / KVB;   // 16
    for (int t = 0; t < NT; ++t) {
        int kv0 = kvBeg + t * KVB;
        uint4 kr[4], vr[4];
        #pragma unroll
        for (int ps = 0; ps < 4; ++ps) {
            kr[ps] = *(const uint4*)(kbase + (long)(kv0 + krow[ps]) * QKLD + kc[ps] * 8);
            vr[ps] = *(const uint4*)(vbase + (long)vd[ps] * Nn_ + kv0 + vc[ps] * 8);
        }
        #pragma unroll
        for (int ps = 0; ps < 4; ++ps) {
            *(uint4*)(Ks + koff[ps]) = kr[ps];
            *(uint4*)(Vs + voff[ps]) = vr[ps];
        }
        __syncthreads();
        // ---- S = Q K^T (log2-domain)
        f32x4 sacc[2];
        #pragma unroll
        for (int j = 0; j < 2; ++j)
            #pragma unroll
            for (int r = 0; r < 4; ++r) sacc[j][r] = 0.f;
        __builtin_amdgcn_s_setprio(1);
        #pragma unroll
        for (int ks = 0; ks < 8; ++ks) {
            #pragma unroll
            for (int j = 0; j < 2; ++j) {
                int row = j * 16 + lr;
                bf16x8 kf = *(const bf16x8*)(Ks + row * 512 +
                            ((ks * 64 + lg * 16) ^ ((row & 7) << 4)));
                sacc[j] = __builtin_amdgcn_mfma_f32_16x16x32_bf16(qf[ks], kf, sacc[j], 0, 0, 0);
            }
        }
        __builtin_amdgcn_s_setprio(0);
        // ---- P = exp2(S) -> Pl
        #pragma unroll
        for (int j = 0; j < 2; ++j)
            #pragma unroll
            for (int r = 0; r < 4; ++r) {
                float p = __builtin_amdgcn_exp2f(sacc[j][r]);
                l_r[r] += p;
                int prow = w * 16 + 4 * lg + r;
                int pp = prow >> 1;
                *(__hip_bfloat16*)(Pl + pp * 128 +
                    ((((prow & 1) * 64) + (j * 16 + lr) * 2) ^ ((pp & 7) << 4))) =
                    __float2bfloat16(p);
            }
        // ---- O += P V^T
        __builtin_amdgcn_s_setprio(1);
        {
            int prow = w * 16 + lr;
            int pp = prow >> 1;
            bf16x8 pf = *(const bf16x8*)(Pl + pp * 128 +
                        ((((prow & 1) * 64) + lg * 16) ^ ((pp & 7) << 4)));
            #pragma unroll
            for (int jd = 0; jd < 16; ++jd) {
                int vrw = jd * 16 + lr;
                int vp = vrw >> 1;
                bf16x8 vf = *(const bf16x8*)(Vs + vp * 128 +
                            ((((vrw & 1) * 64) + lg * 16) ^ ((vp & 7) << 4)));
                Oacc[jd] = __builtin_amdgcn_mfma_f32_16x16x32_bf16(pf, vf, Oacc[jd], 0, 0, 0);
            }
        }
        __builtin_amdgcn_s_setprio(0);
        __syncthreads();
    }

    #pragma unroll
    for (int r = 0; r < 4; ++r) {
        float v = l_r[r];
        #pragma unroll
        for (int off = 1; off <= 8; off <<= 1)
            v += __shfl_xor(v, off);
        l_r[r] = v;
    }

    __hip_bfloat16* Op = Opart + (((long)b * KVSPLIT + sp) * Nn_ + n0) * 256;
    #pragma unroll
    for (int jd = 0; jd < 16; ++jd)
        #pragma unroll
        for (int r = 0; r < 4; ++r) {
            int row = w * 16 + lg * 4 + r;
            Op[(long)row * 256 + jd * 16 + lr] = __float2bfloat16(Oacc[jd][r]);
        }
    if (lr == 0) {
        float* lp = lsum + ((long)b * KVSPLIT + sp) * Nn_ + n0;
        #pragma unroll
        for (int r = 0; r < 4; ++r)
            lp[w * 16 + lg * 4 + r] = l_r[r];
    }
}

// ---------------------------------------------------------------------------
__global__ __launch_bounds__(256) void merge_flash(
    const __hip_bfloat16* __restrict__ Opart, const float* __restrict__ lsum,
    __hip_bfloat16* __restrict__ refsT)
{
    long gi = (long)blockIdx.x * 256 + threadIdx.x;
    long row = gi >> 6;
    int c4 = (int)(gi & 63) * 4;
    long b = row / Nn_, n = row % Nn_;
    float l = 0.f;
    float o0 = 0.f, o1 = 0.f, o2 = 0.f, o3 = 0.f;
    #pragma unroll
    for (int sp = 0; sp < KVSPLIT; ++sp) {
        long rr = (b * KVSPLIT + sp) * Nn_ + n;
        l += lsum[rr];
        union { ushort4 u; __hip_bfloat16 h[4]; } rv;
        rv.u = *(const ushort4*)(Opart + rr * 256 + c4);
        o0 += __bfloat162float(rv.h[0]);
        o1 += __bfloat162float(rv.h[1]);
        o2 += __bfloat162float(rv.h[2]);
        o3 += __bfloat162float(rv.h[3]);
    }
    float dn = 1.0f / l;
    union { ushort4 u; __hip_bfloat16 h[4]; } cv;
    cv.h[0] = __float2bfloat16(o0 * dn);
    cv.h[1] = __float2bfloat16(o1 * dn);
    cv.h[2] = __float2bfloat16(o2 * dn);
    cv.h[3] = __float2bfloat16(o3 * dn);
    *(ushort4*)(refsT + (b * Nn_ + n) * 256 + c4) = cv.u;
}

// ---------------------------------------------------------------------------
// Implicit-GEMM 3x3 conv, 9-way tap-split (1152 blocks). partials bf16.
__global__ __launch_bounds__(256) void conv3x3_gemm(
    const __hip_bfloat16* __restrict__ catT,
    const __hip_bfloat16* __restrict__ Wtap,
    __hip_bfloat16* __restrict__ partials)
{
    __shared__ __align__(16) __hip_bfloat16 As[128 * 32];
    __shared__ __align__(16) __hip_bfloat16 Bs[128 * 32];
    int z = blockIdx.z;
    int b = z / 9, sp = z % 9;
    int dh = sp / 3 - 1, dw = sp % 3 - 1;
    int o0 = blockIdx.x * 128, m0 = blockIdx.y * 128;
    int tid = threadIdx.x;
    int lane = tid & 63, wave = tid >> 6;
    int wr = wave >> 1, wc = wave & 1;
    int lr = lane & 15, lg = lane >> 4;
    const __hip_bfloat16* cb = catT + (long)b * Nn_ * (2 * C);
    const __hip_bfloat16* wt = Wtap + (long)sp * C * (2 * C);

    f32x4 acc[4][4];
    #pragma unroll
    for (int i = 0; i < 4; ++i)
        #pragma unroll
        for (int j = 0; j < 4; ++j)
            #pragma unroll
            for (int r = 0; r < 4; ++r) acc[i][j][r] = 0.f;

    for (int k0 = 0; k0 < 2 * C; k0 += 32) {
        #pragma unroll
        for (int q = 0; q < 2; ++q) {
            int idx = q * 256 + tid;
            int row = idx >> 2;
            int ke = (idx & 3) * 8;
            int gm = m0 + row;
            int h = (gm >> 6) + dh, w2 = (gm & 63) + dw;
            uint4 va = {0, 0, 0, 0};
            if ((unsigned)h < 64u && (unsigned)w2 < 64u)
                va = *(const uint4*)(cb + ((long)((h << 6) + w2)) * (2 * C) + k0 + ke);
            ((uint4*)As)[idx] = va;
            ((uint4*)Bs)[idx] = *(const uint4*)(wt + (long)(o0 + row) * (2 * C) + k0 + ke);
        }
        __syncthreads();
        bf16x8 af[4], bfr[4];
        #pragma unroll
        for (int i = 0; i < 4; ++i)
            af[i] = *(const bf16x8*)(As + (wr * 64 + i * 16 + lr) * 32 + lg * 8);
        #pragma unroll
        for (int j = 0; j < 4; ++j)
            bfr[j] = *(const bf16x8*)(Bs + (wc * 64 + j * 16 + lr) * 32 + lg * 8);
        #pragma unroll
        for (int i = 0; i < 4; ++i)
            #pragma unroll
            for (int j = 0; j < 4; ++j)
                acc[i][j] = __builtin_amdgcn_mfma_f32_16x16x32_bf16(af[i], bfr[j], acc[i][j], 0, 0, 0);
        __syncthreads();
    }

    __hip_bfloat16* Dp = partials + ((long)(b * 9 + sp) * Nn_ + m0) * 256;
    #pragma unroll
    for (int i = 0; i < 4; ++i)
        #pragma unroll
        for (int r = 0; r < 4; ++r) {
            int row = wr * 64 + i * 16 + lg * 4 + r;
            #pragma unroll
            for (int j = 0; j < 4; ++j)
                Dp[(long)row * 256 + o0 + wc * 64 + j * 16 + lr] =
                    __float2bfloat16(acc[i][j][r]);
        }
}

// ---------------------------------------------------------------------------
// Sum 9 bf16 tap-partials -> y1T bf16 with relu (both batches, one launch).
__global__ __launch_bounds__(256) void reduce_partials(
    const __hip_bfloat16* __restrict__ part, long perBatch, long partStride,
    __hip_bfloat16* __restrict__ out, long nPerBatch)
{
    long gi = ((long)blockIdx.x * 256 + threadIdx.x) * 4;
    long total = (long)Bb_ * nPerBatch;
    if (gi >= total) return;
    long b = gi / nPerBatch;
    long i = gi % nPerBatch;
    const __hip_bfloat16* pb = part + b * perBatch;
    float a[4] = {0.f, 0.f, 0.f, 0.f};
    #pragma unroll
    for (int sp = 0; sp < 9; ++sp) {
        union { ushort4 u; __hip_bfloat16 h[4]; } rv;
        rv.u = *(const ushort4*)(pb + (long)sp * partStride + i);
        #pragma unroll
        for (int k = 0; k < 4; ++k) a[k] += __bfloat162float(rv.h[k]);
    }
    union { ushort4 u; __hip_bfloat16 h[4]; } cv;
    #pragma unroll
    for (int k = 0; k < 4; ++k)
        cv.h[k] = __float2bfloat16(fmaxf(a[k], 0.f));
    *(ushort4*)(out + b * nPerBatch + i) = cv.u;
}

// ---------------------------------------------------------------------------
extern "C" void kernel_launch(void* const* d_in, const int* in_sizes, int n_in,
                              void* d_out, int out_size, void* d_ws, size_t ws_size,
                              hipStream_t stream)
{
    const float* qry   = (const float*)d_in[0];
    const float* arch  = (const float*)d_in[1];
    const float* ctx   = (const float*)d_in[2];
    const float* ln1_g = (const float*)d_in[3];
    const float* ln1_b = (const float*)d_in[4];
    const float* Wqkv  = (const float*)d_in[5];
    const float* bqkv  = (const float*)d_in[6];
    const float* Wproj = (const float*)d_in[7];
    const float* bproj = (const float*)d_in[8];
    const float* Wg    = (const float*)d_in[9];
    const float* bg    = (const float*)d_in[10];
    const float* ln2_g = (const float*)d_in[11];
    const float* ln2_b = (const float*)d_in[12];
    const float* Wq    = (const float*)d_in[13];
    const float* bq    = (const float*)d_in[14];
    const float* Wkv   = (const float*)d_in[15];
    const float* bkv   = (const float*)d_in[16];
    const float* Wout  = (const float*)d_in[17];
    const float* bout  = (const float*)d_in[18];
    const float* Wf1   = (const float*)d_in[19];
    const float* Wf2   = (const float*)d_in[20];
    const float* bf2   = (const float*)d_in[21];
    float* out = (float*)d_out;

    const long CN = (long)C * Nn_;
    const long MN = (long)Nn_ * C;
    char* ws = (char*)d_ws;
    size_t off = 0;
    auto alloc = [&](size_t bytes) -> char* {
        char* p = ws + off;
        off += (bytes + 255) & ~size_t(255);
        return p;
    };
    float* lbuf     = (float*)alloc((long)Bb_ * KVSPLIT * Nn_ * 4);
    float* gate     = (float*)alloc(Bb_ * C * 4);
    float* biasCol  = (float*)alloc((long)Bb_ * 3 * C * 4);
    float* ktg      = (float*)alloc((long)Bb_ * NC * C * 4);
    float* sgbp     = (float*)alloc((long)Bb_ * NC * 2 * 4);
    float* vtil     = (float*)alloc((long)Bb_ * C * NC * 4);
    float* meanb    = (float*)alloc((long)Bb_ * Nn_ * 4);
    float* invb     = (float*)alloc((long)Bb_ * Nn_ * 4);
    __hip_bfloat16* Opart = (__hip_bfloat16*)alloc((long)Bb_ * KVSPLIT * MN * 2);
    __hip_bfloat16* convPart = (__hip_bfloat16*)alloc((long)Bb_ * 9 * MN * 2);
    __hip_bfloat16* qryTb = (__hip_bfloat16*)alloc(Bb_ * MN * 2);
    __hip_bfloat16* x1T   = (__hip_bfloat16*)alloc(Bb_ * MN * 2);
    __hip_bfloat16* qkT   = (__hip_bfloat16*)alloc((long)Bb_ * Nn_ * QKLD * 2);
    __hip_bfloat16* vB    = (__hip_bfloat16*)alloc(Bb_ * CN * 2);
    __hip_bfloat16* refsT = (__hip_bfloat16*)alloc(Bb_ * MN * 2);
    __hip_bfloat16* catT  = (__hip_bfloat16*)alloc((long)Bb_ * Nn_ * 2 * C * 2);
    __hip_bfloat16* y1T   = (__hip_bfloat16*)alloc(Bb_ * MN * 2);
    __hip_bfloat16* WqkvG = (__hip_bfloat16*)alloc((long)Bb_ * 3 * C * C * 2);
    __hip_bfloat16* Wprojb= (__hip_bfloat16*)alloc((long)C * C * 2);
    __hip_bfloat16* Wf2b  = (__hip_bfloat16*)alloc((long)C * C * 2);
    __hip_bfloat16* Wtap  = (__hip_bfloat16*)alloc((long)9 * C * 2 * C * 2);

    // 1. layernorm (ln1 only; ln2 folded) + bf16 qry transpose + mean/inv
    lnT_kernel<<<Bb_ * (Nn_ / 64), 256, 0, stream>>>(
        qry, ln1_g, ln1_b, x1T, qryTb, meanb, invb);

    // 2. gate + weight prep + cross prep (LN2 folded)
    gate_kernel<<<Bb_, 256, 0, stream>>>(arch, Wg, bg, gate);
    build_wqkv<<<(Bb_ * 3 * C * C + 255) / 256, 256, 0, stream>>>(Wqkv, bqkv, gate, WqkvG, biasCol);
    {
        long total = (long)C * C * 2 + 9l * C * 2 * C;
        cast_all<<<(int)((total + 255) / 256), 256, 0, stream>>>(
            Wproj, Wf2, Wf1, Wprojb, Wf2b, Wtap);
    }
    cross_prep<<<Bb_ * NC, 256, 0, stream>>>(
        ctx, Wkv, bkv, Wq, bq, Wout, ln2_g, ln2_b, ktg, sgbp, vtil);

    // 3. qkv GEMM with fused v-transpose -> qkT [B][N][512] + vB [B][C][N]
    gemm64_qkv<<<dim3(12, 64, Bb_), 256, 0, stream>>>(
        x1T, WqkvG, biasCol, qkT, vB);

    // 4. flash attention + merge -> refsT bf16 [B][N][C]
    flash_attn<<<dim3(Nn_ / 64, KVSPLIT, Bb_), 256, 0, stream>>>(qkT, vB, Opart, lbuf);
    merge_flash<<<(int)((long)Bb_ * Nn_ * 64 / 256), 256, 0, stream>>>(Opart, lbuf, refsT);

    // 5. catT[:, :256] = qryTb + refsT @ Wproj^T + bproj  (64x64 tiles)
    gemm64<<<dim3(C / 64, Nn_ / 64, Bb_), 256, 0, stream>>>(
        refsT, Wprojb, nullptr, catT, Nn_, C, C, C, C, 2 * C,
        MN, 0, (long)Nn_ * 2 * C,
        nullptr, bproj, 0, nullptr, qryTb, C, MN, 1.0f, 0);

    // 6. catT[:, 256:] = fused cross attention (LN2 folded)
    cross_fused<<<Bb_ * (Nn_ / 64), 256, 0, stream>>>(
        qryTb, meanb, invb, ktg, sgbp, vtil, bout, catT);

    // 7. implicit conv3x3 (9-way tap-split) + fused 2-batch reduce(relu)
    conv3x3_gemm<<<dim3(2, 32, Bb_ * 9), 256, 0, stream>>>(catT, Wtap, convPart);
    reduce_partials<<<(int)((long)Bb_ * MN / 1024), 256, 0, stream>>>(
        convPart, 9 * MN, MN, y1T, MN);

    // 8. out = qry + Wf2 @ y1 + bf2   (fp32 [B][C][N])  (64x64 tiles)
    gemm64<<<dim3(Nn_ / 64, C / 64, Bb_), 256, 0, stream>>>(
        Wf2b, y1T, out, nullptr, C, Nn_, C, C, C, Nn_,
        0, MN, CN,
        bf2, nullptr, 0, qry, nullptr, Nn_, CN, 1.0f, 0);
}

// Round 19
// 202.782 us; speedup vs baseline: 1.5641x; 1.0396x over previous
//
#include <hip/hip_runtime.h>
#include <hip/hip_bf16.h>

#define C 256
#define HID 128
#define Bb_ 2
#define Hh 64
#define Ww 64
#define Nn_ 4096
#define NP 16
#define NC 16
#define KVSPLIT 8
#define KVB 32
#define QKLD (2 * C)   // qkT row stride (q:0..255, k:256..511)

typedef __bf16 bf16x8 __attribute__((ext_vector_type(8)));
typedef float f32x4 __attribute__((ext_vector_type(4)));

// ---------------------------------------------------------------------------
// Coalesced tiled LayerNorm -> x1T bf16 [B][N][C], qryT bf16, mean/inv fp32.
__global__ __launch_bounds__(256) void lnT_kernel(
    const float* __restrict__ x,
    const float* __restrict__ g1, const float* __restrict__ b1,
    __hip_bfloat16* __restrict__ x1T, __hip_bfloat16* __restrict__ qryTb,
    float* __restrict__ meanb, float* __restrict__ invb)
{
    int blk = blockIdx.x;
    int b = blk >> 6;
    int n0 = (blk & 63) << 6;
    int t = threadIdx.x;
    __shared__ __hip_bfloat16 xs[64][258];
    __shared__ float rs4[4][64], rq4[4][64], mean[64], inv[64];
    int j = t & 63, cg = t >> 6;
    float s = 0.f, q = 0.f;
    for (int it = 0; it < 64; ++it) {
        int c = it * 4 + cg;
        float v = x[((long)b * C + c) * Nn_ + n0 + j];
        xs[j][c] = __float2bfloat16(v);
        s += v; q += v * v;
    }
    rs4[cg][j] = s; rq4[cg][j] = q;
    __syncthreads();
    if (t < 64) {
        float S = rs4[0][t] + rs4[1][t] + rs4[2][t] + rs4[3][t];
        float Q = rq4[0][t] + rq4[1][t] + rq4[2][t] + rq4[3][t];
        float m = S * (1.0f / C);
        float var = Q * (1.0f / C) - m * m;
        mean[t] = m; inv[t] = rsqrtf(var + 1e-5f);
        meanb[(long)b * Nn_ + n0 + t] = m;
        invb[(long)b * Nn_ + n0 + t] = inv[t];
    }
    __syncthreads();
    float G1 = g1[t], B1 = b1[t];
    for (int j2 = 0; j2 < 64; ++j2) {
        float v = __bfloat162float(xs[j2][t]);
        float xn = (v - mean[j2]) * inv[j2];
        long o = ((long)b * Nn_ + n0 + j2) * C + t;
        x1T[o] = __float2bfloat16(xn * G1 + B1);
        qryTb[o] = xs[j2][t];
    }
}

// ---------------------------------------------------------------------------
// Fused prep: block roles -> [0,nCast): weight casts; [nCast,nCast+2): gate;
// [nCast+2, nCast+2+32): cross_prep (LN2 folded). All independent.
#define NCAST 5120
__global__ __launch_bounds__(256) void prep_fused(
    // cast inputs
    const float* __restrict__ Wproj, const float* __restrict__ Wf2,
    const float* __restrict__ Wf1,
    __hip_bfloat16* __restrict__ Wprojb, __hip_bfloat16* __restrict__ Wf2b,
    __hip_bfloat16* __restrict__ Wtap,
    // gate inputs
    const float* __restrict__ arch, const float* __restrict__ Wg,
    const float* __restrict__ bg, float* __restrict__ gate,
    // cross_prep inputs
    const float* __restrict__ ctx, const float* __restrict__ Wkv,
    const float* __restrict__ bkv, const float* __restrict__ Wq,
    const float* __restrict__ bq, const float* __restrict__ Wout,
    const float* __restrict__ g2, const float* __restrict__ b2,
    float* __restrict__ ktg, float* __restrict__ sgbp,
    float* __restrict__ vtil)
{
    __shared__ float sh[768];
    int bz = blockIdx.x;
    int t = threadIdx.x;
    if (bz < NCAST) {
        long i = (long)bz * 256 + t;
        const long nP = (long)C * C;
        const long nT = 9l * C * 2 * C;
        if (i < nP) { Wprojb[i] = __float2bfloat16(Wproj[i]); return; }
        i -= nP;
        if (i < nP) { Wf2b[i] = __float2bfloat16(Wf2[i]); return; }
        i -= nP;
        if (i < nT) {
            int tap = (int)(i / (C * 2 * C));
            long rem = i % (C * 2 * C);
            int o = (int)(rem / (2 * C)), ic = (int)(rem % (2 * C));
            Wtap[i] = __float2bfloat16(Wf1[((long)o * 2 * C + ic) * 9 + tap]);
        }
        return;
    }
    if (bz < NCAST + 2) {
        int b = bz - NCAST;
        float* guide = sh;
        float s = 0.f;
        for (int p = 0; p < NP; ++p) s += arch[(long)b * NP * C + (long)p * C + t];
        guide[t] = s * (1.0f / NP);
        __syncthreads();
        float acc = bg[t];
        for (int cc = 0; cc < C; ++cc) acc += guide[cc] * Wg[(long)t * C + cc];
        gate[b * C + t] = 1.0f / (1.0f + __expf(-acc));
        return;
    }
    {
        int idx = bz - NCAST - 2;
        int b = idx >> 4, m = idx & 15;
        float* cs = sh;
        float* kl = sh + 256;
        float* red = sh + 512;
        cs[t] = ctx[((long)b * NC + m) * C + t];
        __syncthreads();
        float acc = bkv[t];
        for (int c = 0; c < C; ++c) acc += cs[c] * Wkv[(long)t * C + c];
        kl[t] = acc;
        __syncthreads();
        const float scc = 0.08838834764831845f;  // 1/sqrt(128)
        float kt = 0.f;
        for (int h = 0; h < HID; ++h) kt += kl[h] * Wq[(long)h * C + t];
        kt *= scc;
        float G2 = g2[t], B2 = b2[t];
        ktg[((long)b * NC + m) * C + t] = kt * G2;
        float vt = 0.f;
        for (int h = 0; h < HID; ++h) vt += kl[HID + h] * Wout[(long)t * HID + h];
        vtil[((long)b * C + t) * NC + m] = vt;
        red[t] = kt * G2;
        __syncthreads();
        for (int s = 128; s > 0; s >>= 1) {
            if (t < s) red[t] += red[t + s];
            __syncthreads();
        }
        float sg = red[0];
        __syncthreads();
        red[t] = kt * B2 + ((t < 128) ? scc * bq[t] * kl[t] : 0.f);
        __syncthreads();
        for (int s = 128; s > 0; s >>= 1) {
            if (t < s) red[t] += red[t + s];
            __syncthreads();
        }
        if (t == 0) {
            sgbp[(b * NC + m) * 2] = sg;
            sgbp[(b * NC + m) * 2 + 1] = red[0];
        }
    }
}

// ---------------------------------------------------------------------------
#define QSCALE 0.09016844005429271f   // log2(e)/16
__global__ __launch_bounds__(256) void build_wqkv(
    const float* __restrict__ Wqkv, const float* __restrict__ bqkv,
    const float* __restrict__ gate,
    __hip_bfloat16* __restrict__ WqkvG, float* __restrict__ biasCol)
{
    long i = (long)blockIdx.x * 256 + threadIdx.x;
    long total = (long)Bb_ * 3 * C * C;
    if (i < total) {
        long b = i / (3 * C * C);
        long rem = i % (3 * C * C);
        int o = (int)(rem / C);
        float v = Wqkv[rem];
        if (o < C) v *= QSCALE;
        else if (o < 2 * C) v *= gate[b * C + (o - C)];
        WqkvG[i] = __float2bfloat16(v);
    }
    if (i < (long)Bb_ * 3 * C) {
        long b = i / (3 * C);
        int o = (int)(i % (3 * C));
        float v = bqkv[o];
        if (o < C) v *= QSCALE;
        else if (o < 2 * C) v *= gate[b * C + (o - C)];
        biasCol[i] = v;
    }
}

// ---------------------------------------------------------------------------
// Fused cross attention (LN2 folded) -> catT right half.
__global__ __launch_bounds__(256) void cross_fused(
    const __hip_bfloat16* __restrict__ qryTb,
    const float* __restrict__ meanb, const float* __restrict__ invb,
    const float* __restrict__ ktg, const float* __restrict__ sgbp,
    const float* __restrict__ vtil, const float* __restrict__ bout,
    __hip_bfloat16* __restrict__ catT)
{
    int blk = blockIdx.x;
    int b = blk >> 6;
    long n = (long)(blk & 63) * 64 + (threadIdx.x >> 2);
    int cg = threadIdx.x & 3;
    int t = threadIdx.x;
    __shared__ float kt[NC * C];
    __shared__ float vt[C * NC];
    for (int r = 0; r < 16; ++r) {
        int idx = r * 256 + t;
        int m = idx >> 8, c = idx & 255;
        kt[m * 256 + (c & 63) * 4 + (c >> 6)] = ktg[((long)b * NC + m) * C + c];
        int c2 = idx >> 4, m2 = idx & 15;
        vt[((c2 & 63) * 4 + (c2 >> 6)) * 16 + m2] = vtil[((long)b * C + c2) * NC + m2];
    }
    __syncthreads();

    float mu = meanb[(long)b * Nn_ + n];
    float sig = invb[(long)b * Nn_ + n];

    float s[NC];
    #pragma unroll
    for (int m = 0; m < NC; ++m) s[m] = 0.f;
    const __hip_bfloat16* xr = qryTb + ((long)b * Nn_ + n) * C + cg * 64;
    for (int c8 = 0; c8 < 8; ++c8) {
        bf16x8 xv = *(const bf16x8*)(xr + c8 * 8);
        #pragma unroll
        for (int e = 0; e < 8; ++e) {
            float xf = (float)xv[e];
            int ic = c8 * 8 + e;
            #pragma unroll
            for (int m = 0; m < NC; ++m)
                s[m] += xf * kt[m * 256 + ic * 4 + cg];
        }
    }
    #pragma unroll
    for (int m = 0; m < NC; ++m) {
        s[m] += __shfl_xor(s[m], 1);
        s[m] += __shfl_xor(s[m], 2);
        s[m] = sig * s[m] - mu * sig * sgbp[(b * NC + m) * 2] + sgbp[(b * NC + m) * 2 + 1];
    }
    float mx = -1e30f;
    #pragma unroll
    for (int m = 0; m < NC; ++m) mx = fmaxf(mx, s[m]);
    float sum = 0.f;
    #pragma unroll
    for (int m = 0; m < NC; ++m) { s[m] = __expf(s[m] - mx); sum += s[m]; }
    float dn = 1.0f / sum;

    const __hip_bfloat16* qr = qryTb + ((long)b * Nn_ + n) * C + cg * 64;
    __hip_bfloat16* outp = catT + ((long)b * Nn_ + n) * (2 * C) + C + cg * 64;
    for (int c8 = 0; c8 < 8; ++c8) {
        union { ushort4 u; __hip_bfloat16 h[4]; } cv0, cv1;
        #pragma unroll
        for (int e = 0; e < 8; ++e) {
            int ic = c8 * 8 + e;
            int c = cg * 64 + ic;
            float acc = __bfloat162float(qr[ic]) + bout[c];
            float pv = 0.f;
            #pragma unroll
            for (int m = 0; m < NC; ++m)
                pv += vt[(ic * 4 + cg) * 16 + m] * s[m];
            acc += pv * dn;
            if (e < 4) cv0.h[e] = __float2bfloat16(acc);
            else       cv1.h[e - 4] = __float2bfloat16(acc);
        }
        *(ushort4*)(outp + c8 * 8) = cv0.u;
        *(ushort4*)(outp + c8 * 8 + 4) = cv1.u;
    }
}

// ---------------------------------------------------------------------------
// 64x64-tile MFMA bf16 GEMM (high occupancy) for projection GEMMs.
__global__ __launch_bounds__(256) void gemm64(
    const __hip_bfloat16* __restrict__ A,
    const __hip_bfloat16* __restrict__ Bt,
    float* __restrict__ D,
    __hip_bfloat16* __restrict__ Dbf,
    int M, int N, int K, int lda, int ldb, int ldd,
    long batchA, long batchB, long batchD,
    const float* __restrict__ biasRow,
    const float* __restrict__ biasCol, long bcStride,
    const float* __restrict__ resid,
    const __hip_bfloat16* __restrict__ residB, int ldr, long batchR,
    float alpha, int relu)
{
    __shared__ __align__(16) __hip_bfloat16 As[64 * 32];
    __shared__ __align__(16) __hip_bfloat16 Bs[64 * 32];
    int bz = blockIdx.z;
    const __hip_bfloat16* Ab = A + (long)bz * batchA;
    const __hip_bfloat16* Bb = Bt + (long)bz * batchB;
    int m0 = blockIdx.y * 64, n0 = blockIdx.x * 64;
    int tid = threadIdx.x;
    int lane = tid & 63, wave = tid >> 6;
    int wr = wave >> 1, wc = wave & 1;
    int lr = lane & 15, lg = lane >> 4;
    int srow = tid >> 2, ske = (tid & 3) * 8;

    f32x4 acc[2][2];
    #pragma unroll
    for (int i = 0; i < 2; ++i)
        #pragma unroll
        for (int j = 0; j < 2; ++j)
            #pragma unroll
            for (int r = 0; r < 4; ++r) acc[i][j][r] = 0.f;

    for (int k0 = 0; k0 < K; k0 += 32) {
        uint4 va = *(const uint4*)(Ab + (long)(m0 + srow) * lda + k0 + ske);
        uint4 vb = *(const uint4*)(Bb + (long)(n0 + srow) * ldb + k0 + ske);
        ((uint4*)As)[tid] = va;
        ((uint4*)Bs)[tid] = vb;
        __syncthreads();
        bf16x8 af[2], bfr[2];
        #pragma unroll
        for (int i = 0; i < 2; ++i)
            af[i] = *(const bf16x8*)(As + (wr * 32 + i * 16 + lr) * 32 + lg * 8);
        #pragma unroll
        for (int j = 0; j < 2; ++j)
            bfr[j] = *(const bf16x8*)(Bs + (wc * 32 + j * 16 + lr) * 32 + lg * 8);
        #pragma unroll
        for (int i = 0; i < 2; ++i)
            #pragma unroll
            for (int j = 0; j < 2; ++j)
                acc[i][j] = __builtin_amdgcn_mfma_f32_16x16x32_bf16(af[i], bfr[j], acc[i][j], 0, 0, 0);
        __syncthreads();
    }

    int colc = n0 + wc * 32 + lr;
    #pragma unroll
    for (int i = 0; i < 2; ++i) {
        #pragma unroll
        for (int r = 0; r < 4; ++r) {
            int row = m0 + wr * 32 + i * 16 + lg * 4 + r;
            float brv = biasRow ? biasRow[row] : 0.f;
            #pragma unroll
            for (int j = 0; j < 2; ++j) {
                int cc = colc + j * 16;
                float v = acc[i][j][r] * alpha + brv;
                if (biasCol) v += biasCol[bz * bcStride + cc];
                if (resid) v += resid[(long)bz * batchR + (long)row * ldr + cc];
                if (residB) v += __bfloat162float(residB[(long)bz * batchR + (long)row * ldr + cc]);
                if (relu) v = fmaxf(v, 0.f);
                long oa = (long)bz * batchD + (long)row * ldd + cc;
                if (Dbf) Dbf[oa] = __float2bfloat16(v);
                else     D[oa] = v;
            }
        }
    }
}

// ---------------------------------------------------------------------------
// qkv GEMM with fused v-transpose.
__global__ __launch_bounds__(256) void gemm64_qkv(
    const __hip_bfloat16* __restrict__ A,      // x1T [B][N][C]
    const __hip_bfloat16* __restrict__ Bt,     // WqkvG [B][768][C]
    const float* __restrict__ biasCol,         // [B][768]
    __hip_bfloat16* __restrict__ qkT,          // [B][N][512]
    __hip_bfloat16* __restrict__ vB)           // [B][C][N]
{
    __shared__ __align__(16) __hip_bfloat16 As[64 * 32];
    __shared__ __align__(16) __hip_bfloat16 Bs[64 * 32];
    __shared__ __hip_bfloat16 tb[64][66];
    int bz = blockIdx.z;
    const __hip_bfloat16* Ab = A + (long)bz * Nn_ * C;
    const __hip_bfloat16* Bb = Bt + (long)bz * 3 * C * C;
    int m0 = blockIdx.y * 64, n0 = blockIdx.x * 64;
    int tid = threadIdx.x;
    int lane = tid & 63, wave = tid >> 6;
    int wr = wave >> 1, wc = wave & 1;
    int lr = lane & 15, lg = lane >> 4;
    int srow = tid >> 2, ske = (tid & 3) * 8;

    f32x4 acc[2][2];
    #pragma unroll
    for (int i = 0; i < 2; ++i)
        #pragma unroll
        for (int j = 0; j < 2; ++j)
            #pragma unroll
            for (int r = 0; r < 4; ++r) acc[i][j][r] = 0.f;

    for (int k0 = 0; k0 < C; k0 += 32) {
        uint4 va = *(const uint4*)(Ab + (long)(m0 + srow) * C + k0 + ske);
        uint4 vb = *(const uint4*)(Bb + (long)(n0 + srow) * C + k0 + ske);
        ((uint4*)As)[tid] = va;
        ((uint4*)Bs)[tid] = vb;
        __syncthreads();
        bf16x8 af[2], bfr[2];
        #pragma unroll
        for (int i = 0; i < 2; ++i)
            af[i] = *(const bf16x8*)(As + (wr * 32 + i * 16 + lr) * 32 + lg * 8);
        #pragma unroll
        for (int j = 0; j < 2; ++j)
            bfr[j] = *(const bf16x8*)(Bs + (wc * 32 + j * 16 + lr) * 32 + lg * 8);
        #pragma unroll
        for (int i = 0; i < 2; ++i)
            #pragma unroll
            for (int j = 0; j < 2; ++j)
                acc[i][j] = __builtin_amdgcn_mfma_f32_16x16x32_bf16(af[i], bfr[j], acc[i][j], 0, 0, 0);
        __syncthreads();
    }

    if (n0 < 2 * C) {
        #pragma unroll
        for (int i = 0; i < 2; ++i)
            #pragma unroll
            for (int r = 0; r < 4; ++r) {
                int row = m0 + wr * 32 + i * 16 + lg * 4 + r;
                #pragma unroll
                for (int j = 0; j < 2; ++j) {
                    int cc = n0 + wc * 32 + lr + j * 16;
                    float v = acc[i][j][r] + biasCol[bz * 3 * C + cc];
                    qkT[((long)bz * Nn_ + row) * QKLD + cc] = __float2bfloat16(v);
                }
            }
    } else {
        #pragma unroll
        for (int i = 0; i < 2; ++i)
            #pragma unroll
            for (int r = 0; r < 4; ++r) {
                int rowl = wr * 32 + i * 16 + lg * 4 + r;
                #pragma unroll
                for (int j = 0; j < 2; ++j) {
                    int coll = wc * 32 + lr + j * 16;
                    float v = acc[i][j][r] + biasCol[bz * 3 * C + n0 + coll];
                    tb[coll][rowl] = __float2bfloat16(v);
                }
            }
        __syncthreads();
        int c0 = n0 - 2 * C;
        #pragma unroll
        for (int it = 0; it < 8; ++it) {
            int rowl = it * 8 + (tid >> 5);
            int cp = tid & 31;
            __hip_bfloat16* dst = vB + ((long)bz * C + c0 + rowl) * Nn_ + m0 + cp * 2;
            dst[0] = tb[rowl][cp * 2];
            dst[1] = tb[rowl][cp * 2 + 1];
        }
    }
}

// ---------------------------------------------------------------------------
// Flash attention (round-12 structure; frozen).
__global__ __launch_bounds__(256) void flash_attn(
    const __hip_bfloat16* __restrict__ qkT,
    const __hip_bfloat16* __restrict__ vB,
    __hip_bfloat16* __restrict__ Opart,   // [B][KVSPLIT][N][256] bf16
    float* __restrict__ lsum)             // [B][KVSPLIT][N]
{
    int qb = blockIdx.x, sp = blockIdx.y, b = blockIdx.z;
    int n0 = qb * 64;
    int tid = threadIdx.x;
    int lane = tid & 63, w = tid >> 6;
    int lr = lane & 15, lg = lane >> 4;

    __shared__ __align__(16) char Ks[32 * 512];
    __shared__ __align__(16) char Vs[128 * 128];
    __shared__ __align__(16) char Pl[32 * 128];

    bf16x8 qf[8];
    {
        const __hip_bfloat16* qp = qkT + ((long)b * Nn_ + n0 + w * 16 + lr) * QKLD;
        #pragma unroll
        for (int ks = 0; ks < 8; ++ks)
            qf[ks] = *(const bf16x8*)(qp + ks * 32 + lg * 8);
    }

    const __hip_bfloat16* kbase = qkT + ((long)b * Nn_) * QKLD + C;
    const __hip_bfloat16* vbase = vB + (long)b * C * Nn_;
    int kvBeg = sp * (Nn_ / KVSPLIT);

    int krow[4], kc[4], koff[4], vd[4], vc[4], voff[4];
    #pragma unroll
    for (int ps = 0; ps < 4; ++ps) {
        int id = ps * 256 + tid;
        krow[ps] = id >> 5; kc[ps] = id & 31;
        koff[ps] = krow[ps] * 512 + ((kc[ps] * 16) ^ ((krow[ps] & 7) << 4));
        vd[ps] = id >> 2; vc[ps] = id & 3;
        int vp = vd[ps] >> 1;
        voff[ps] = vp * 128 + ((((vd[ps] & 1) * 64) + vc[ps] * 16) ^ ((vp & 7) << 4));
    }

    f32x4 Oacc[16];
    #pragma unroll
    for (int jd = 0; jd < 16; ++jd)
        #pragma unroll
        for (int r = 0; r < 4; ++r) Oacc[jd][r] = 0.f;
    float l_r[4] = {0.f, 0.f, 0.f, 0.f};

    const int NT = (Nn_ / KVSPLIT) / KVB;   // 16
    for (int t = 0; t < NT; ++t) {
        int kv0 = kvBeg + t * KVB;
        uint4 kr[4], vr[4];
        #pragma unroll
        for (int ps = 0; ps < 4; ++ps) {
            kr[ps] = *(const uint4*)(kbase + (long)(kv0 + krow[ps]) * QKLD + kc[ps] * 8);
            vr[ps] = *(const uint4*)(vbase + (long)vd[ps] * Nn_ + kv0 + vc[ps] * 8);
        }
        #pragma unroll
        for (int ps = 0; ps < 4; ++ps) {
            *(uint4*)(Ks + koff[ps]) = kr[ps];
            *(uint4*)(Vs + voff[ps]) = vr[ps];
        }
        __syncthreads();
        // ---- S = Q K^T (log2-domain)
        f32x4 sacc[2];
        #pragma unroll
        for (int j = 0; j < 2; ++j)
            #pragma unroll
            for (int r = 0; r < 4; ++r) sacc[j][r] = 0.f;
        __builtin_amdgcn_s_setprio(1);
        #pragma unroll
        for (int ks = 0; ks < 8; ++ks) {
            #pragma unroll
            for (int j = 0; j < 2; ++j) {
                int row = j * 16 + lr;
                bf16x8 kf = *(const bf16x8*)(Ks + row * 512 +
                            ((ks * 64 + lg * 16) ^ ((row & 7) << 4)));
                sacc[j] = __builtin_amdgcn_mfma_f32_16x16x32_bf16(qf[ks], kf, sacc[j], 0, 0, 0);
            }
        }
        __builtin_amdgcn_s_setprio(0);
        // ---- P = exp2(S) -> Pl
        #pragma unroll
        for (int j = 0; j < 2; ++j)
            #pragma unroll
            for (int r = 0; r < 4; ++r) {
                float p = __builtin_amdgcn_exp2f(sacc[j][r]);
                l_r[r] += p;
                int prow = w * 16 + 4 * lg + r;
                int pp = prow >> 1;
                *(__hip_bfloat16*)(Pl + pp * 128 +
                    ((((prow & 1) * 64) + (j * 16 + lr) * 2) ^ ((pp & 7) << 4))) =
                    __float2bfloat16(p);
            }
        // ---- O += P V^T
        __builtin_amdgcn_s_setprio(1);
        {
            int prow = w * 16 + lr;
            int pp = prow >> 1;
            bf16x8 pf = *(const bf16x8*)(Pl + pp * 128 +
                        ((((prow & 1) * 64) + lg * 16) ^ ((pp & 7) << 4)));
            #pragma unroll
            for (int jd = 0; jd < 16; ++jd) {
                int vrw = jd * 16 + lr;
                int vp = vrw >> 1;
                bf16x8 vf = *(const bf16x8*)(Vs + vp * 128 +
                            ((((vrw & 1) * 64) + lg * 16) ^ ((vp & 7) << 4)));
                Oacc[jd] = __builtin_amdgcn_mfma_f32_16x16x32_bf16(pf, vf, Oacc[jd], 0, 0, 0);
            }
        }
        __builtin_amdgcn_s_setprio(0);
        __syncthreads();
    }

    #pragma unroll
    for (int r = 0; r < 4; ++r) {
        float v = l_r[r];
        #pragma unroll
        for (int off = 1; off <= 8; off <<= 1)
            v += __shfl_xor(v, off);
        l_r[r] = v;
    }

    __hip_bfloat16* Op = Opart + (((long)b * KVSPLIT + sp) * Nn_ + n0) * 256;
    #pragma unroll
    for (int jd = 0; jd < 16; ++jd)
        #pragma unroll
        for (int r = 0; r < 4; ++r) {
            int row = w * 16 + lg * 4 + r;
            Op[(long)row * 256 + jd * 16 + lr] = __float2bfloat16(Oacc[jd][r]);
        }
    if (lr == 0) {
        float* lp = lsum + ((long)b * KVSPLIT + sp) * Nn_ + n0;
        #pragma unroll
        for (int r = 0; r < 4; ++r)
            lp[w * 16 + lg * 4 + r] = l_r[r];
    }
}

// ---------------------------------------------------------------------------
__global__ __launch_bounds__(256) void merge_flash(
    const __hip_bfloat16* __restrict__ Opart, const float* __restrict__ lsum,
    __hip_bfloat16* __restrict__ refsT)
{
    long gi = (long)blockIdx.x * 256 + threadIdx.x;
    long row = gi >> 6;
    int c4 = (int)(gi & 63) * 4;
    long b = row / Nn_, n = row % Nn_;
    float l = 0.f;
    float o0 = 0.f, o1 = 0.f, o2 = 0.f, o3 = 0.f;
    #pragma unroll
    for (int sp = 0; sp < KVSPLIT; ++sp) {
        long rr = (b * KVSPLIT + sp) * Nn_ + n;
        l += lsum[rr];
        union { ushort4 u; __hip_bfloat16 h[4]; } rv;
        rv.u = *(const ushort4*)(Opart + rr * 256 + c4);
        o0 += __bfloat162float(rv.h[0]);
        o1 += __bfloat162float(rv.h[1]);
        o2 += __bfloat162float(rv.h[2]);
        o3 += __bfloat162float(rv.h[3]);
    }
    float dn = 1.0f / l;
    union { ushort4 u; __hip_bfloat16 h[4]; } cv;
    cv.h[0] = __float2bfloat16(o0 * dn);
    cv.h[1] = __float2bfloat16(o1 * dn);
    cv.h[2] = __float2bfloat16(o2 * dn);
    cv.h[3] = __float2bfloat16(o3 * dn);
    *(ushort4*)(refsT + (b * Nn_ + n) * 256 + c4) = cv.u;
}

// ---------------------------------------------------------------------------
// Implicit-GEMM 3x3 conv, 9-way tap-split with TAP-ADJACENT dispatch order:
// x = o_blk*9 + sp so the 9 taps sharing a catT slab are dispatch-neighbors
// (L2/L3-warm re-reads instead of 9 distant full sweeps).
__global__ __launch_bounds__(256) void conv3x3_gemm(
    const __hip_bfloat16* __restrict__ catT,
    const __hip_bfloat16* __restrict__ Wtap,
    __hip_bfloat16* __restrict__ partials)
{
    __shared__ __align__(16) __hip_bfloat16 As[128 * 32];
    __shared__ __align__(16) __hip_bfloat16 Bs[128 * 32];
    int xx = blockIdx.x;
    int o_blk = xx / 9, sp = xx % 9;
    int dh = sp / 3 - 1, dw = sp % 3 - 1;
    int o0 = o_blk * 128, m0 = blockIdx.y * 128;
    int b = blockIdx.z;
    int tid = threadIdx.x;
    int lane = tid & 63, wave = tid >> 6;
    int wr = wave >> 1, wc = wave & 1;
    int lr = lane & 15, lg = lane >> 4;
    const __hip_bfloat16* cb = catT + (long)b * Nn_ * (2 * C);
    const __hip_bfloat16* wt = Wtap + (long)sp * C * (2 * C);

    f32x4 acc[4][4];
    #pragma unroll
    for (int i = 0; i < 4; ++i)
        #pragma unroll
        for (int j = 0; j < 4; ++j)
            #pragma unroll
            for (int r = 0; r < 4; ++r) acc[i][j][r] = 0.f;

    for (int k0 = 0; k0 < 2 * C; k0 += 32) {
        #pragma unroll
        for (int q = 0; q < 2; ++q) {
            int idx = q * 256 + tid;
            int row = idx >> 2;
            int ke = (idx & 3) * 8;
            int gm = m0 + row;
            int h = (gm >> 6) + dh, w2 = (gm & 63) + dw;
            uint4 va = {0, 0, 0, 0};
            if ((unsigned)h < 64u && (unsigned)w2 < 64u)
                va = *(const uint4*)(cb + ((long)((h << 6) + w2)) * (2 * C) + k0 + ke);
            ((uint4*)As)[idx] = va;
            ((uint4*)Bs)[idx] = *(const uint4*)(wt + (long)(o0 + row) * (2 * C) + k0 + ke);
        }
        __syncthreads();
        bf16x8 af[4], bfr[4];
        #pragma unroll
        for (int i = 0; i < 4; ++i)
            af[i] = *(const bf16x8*)(As + (wr * 64 + i * 16 + lr) * 32 + lg * 8);
        #pragma unroll
        for (int j = 0; j < 4; ++j)
            bfr[j] = *(const bf16x8*)(Bs + (wc * 64 + j * 16 + lr) * 32 + lg * 8);
        #pragma unroll
        for (int i = 0; i < 4; ++i)
            #pragma unroll
            for (int j = 0; j < 4; ++j)
                acc[i][j] = __builtin_amdgcn_mfma_f32_16x16x32_bf16(af[i], bfr[j], acc[i][j], 0, 0, 0);
        __syncthreads();
    }

    __hip_bfloat16* Dp = partials + ((long)(b * 9 + sp) * Nn_ + m0) * 256;
    #pragma unroll
    for (int i = 0; i < 4; ++i)
        #pragma unroll
        for (int r = 0; r < 4; ++r) {
            int row = wr * 64 + i * 16 + lg * 4 + r;
            #pragma unroll
            for (int j = 0; j < 4; ++j)
                Dp[(long)row * 256 + o0 + wc * 64 + j * 16 + lr] =
                    __float2bfloat16(acc[i][j][r]);
        }
}

// ---------------------------------------------------------------------------
// Sum 9 bf16 tap-partials -> y1T bf16 with relu (both batches, one launch).
__global__ __launch_bounds__(256) void reduce_partials(
    const __hip_bfloat16* __restrict__ part, long perBatch, long partStride,
    __hip_bfloat16* __restrict__ out, long nPerBatch)
{
    long gi = ((long)blockIdx.x * 256 + threadIdx.x) * 4;
    long total = (long)Bb_ * nPerBatch;
    if (gi >= total) return;
    long b = gi / nPerBatch;
    long i = gi % nPerBatch;
    const __hip_bfloat16* pb = part + b * perBatch;
    float a[4] = {0.f, 0.f, 0.f, 0.f};
    #pragma unroll
    for (int sp = 0; sp < 9; ++sp) {
        union { ushort4 u; __hip_bfloat16 h[4]; } rv;
        rv.u = *(const ushort4*)(pb + (long)sp * partStride + i);
        #pragma unroll
        for (int k = 0; k < 4; ++k) a[k] += __bfloat162float(rv.h[k]);
    }
    union { ushort4 u; __hip_bfloat16 h[4]; } cv;
    #pragma unroll
    for (int k = 0; k < 4; ++k)
        cv.h[k] = __float2bfloat16(fmaxf(a[k], 0.f));
    *(ushort4*)(out + b * nPerBatch + i) = cv.u;
}

// ---------------------------------------------------------------------------
extern "C" void kernel_launch(void* const* d_in, const int* in_sizes, int n_in,
                              void* d_out, int out_size, void* d_ws, size_t ws_size,
                              hipStream_t stream)
{
    const float* qry   = (const float*)d_in[0];
    const float* arch  = (const float*)d_in[1];
    const float* ctx   = (const float*)d_in[2];
    const float* ln1_g = (const float*)d_in[3];
    const float* ln1_b = (const float*)d_in[4];
    const float* Wqkv  = (const float*)d_in[5];
    const float* bqkv  = (const float*)d_in[6];
    const float* Wproj = (const float*)d_in[7];
    const float* bproj = (const float*)d_in[8];
    const float* Wg    = (const float*)d_in[9];
    const float* bg    = (const float*)d_in[10];
    const float* ln2_g = (const float*)d_in[11];
    const float* ln2_b = (const float*)d_in[12];
    const float* Wq    = (const float*)d_in[13];
    const float* bq    = (const float*)d_in[14];
    const float* Wkv   = (const float*)d_in[15];
    const float* bkv   = (const float*)d_in[16];
    const float* Wout  = (const float*)d_in[17];
    const float* bout  = (const float*)d_in[18];
    const float* Wf1   = (const float*)d_in[19];
    const float* Wf2   = (const float*)d_in[20];
    const float* bf2   = (const float*)d_in[21];
    float* out = (float*)d_out;

    const long CN = (long)C * Nn_;
    const long MN = (long)Nn_ * C;
    char* ws = (char*)d_ws;
    size_t off = 0;
    auto alloc = [&](size_t bytes) -> char* {
        char* p = ws + off;
        off += (bytes + 255) & ~size_t(255);
        return p;
    };
    float* lbuf     = (float*)alloc((long)Bb_ * KVSPLIT * Nn_ * 4);
    float* gate     = (float*)alloc(Bb_ * C * 4);
    float* biasCol  = (float*)alloc((long)Bb_ * 3 * C * 4);
    float* ktg      = (float*)alloc((long)Bb_ * NC * C * 4);
    float* sgbp     = (float*)alloc((long)Bb_ * NC * 2 * 4);
    float* vtil     = (float*)alloc((long)Bb_ * C * NC * 4);
    float* meanb    = (float*)alloc((long)Bb_ * Nn_ * 4);
    float* invb     = (float*)alloc((long)Bb_ * Nn_ * 4);
    __hip_bfloat16* Opart = (__hip_bfloat16*)alloc((long)Bb_ * KVSPLIT * MN * 2);
    __hip_bfloat16* convPart = (__hip_bfloat16*)alloc((long)Bb_ * 9 * MN * 2);
    __hip_bfloat16* qryTb = (__hip_bfloat16*)alloc(Bb_ * MN * 2);
    __hip_bfloat16* x1T   = (__hip_bfloat16*)alloc(Bb_ * MN * 2);
    __hip_bfloat16* qkT   = (__hip_bfloat16*)alloc((long)Bb_ * Nn_ * QKLD * 2);
    __hip_bfloat16* vB    = (__hip_bfloat16*)alloc(Bb_ * CN * 2);
    __hip_bfloat16* refsT = (__hip_bfloat16*)alloc(Bb_ * MN * 2);
    __hip_bfloat16* catT  = (__hip_bfloat16*)alloc((long)Bb_ * Nn_ * 2 * C * 2);
    __hip_bfloat16* y1T   = (__hip_bfloat16*)alloc(Bb_ * MN * 2);
    __hip_bfloat16* WqkvG = (__hip_bfloat16*)alloc((long)Bb_ * 3 * C * C * 2);
    __hip_bfloat16* Wprojb= (__hip_bfloat16*)alloc((long)C * C * 2);
    __hip_bfloat16* Wf2b  = (__hip_bfloat16*)alloc((long)C * C * 2);
    __hip_bfloat16* Wtap  = (__hip_bfloat16*)alloc((long)9 * C * 2 * C * 2);

    // 1. layernorm (ln1; ln2 folded) + bf16 qry transpose + mean/inv
    lnT_kernel<<<Bb_ * (Nn_ / 64), 256, 0, stream>>>(
        qry, ln1_g, ln1_b, x1T, qryTb, meanb, invb);

    // 2. fused prep (casts + gate + cross_prep), then gated wqkv build
    prep_fused<<<NCAST + 2 + Bb_ * NC, 256, 0, stream>>>(
        Wproj, Wf2, Wf1, Wprojb, Wf2b, Wtap,
        arch, Wg, bg, gate,
        ctx, Wkv, bkv, Wq, bq, Wout, ln2_g, ln2_b, ktg, sgbp, vtil);
    build_wqkv<<<(Bb_ * 3 * C * C + 255) / 256, 256, 0, stream>>>(Wqkv, bqkv, gate, WqkvG, biasCol);

    // 3. qkv GEMM with fused v-transpose -> qkT [B][N][512] + vB [B][C][N]
    gemm64_qkv<<<dim3(12, 64, Bb_), 256, 0, stream>>>(
        x1T, WqkvG, biasCol, qkT, vB);

    // 4. flash attention + merge -> refsT bf16 [B][N][C]
    flash_attn<<<dim3(Nn_ / 64, KVSPLIT, Bb_), 256, 0, stream>>>(qkT, vB, Opart, lbuf);
    merge_flash<<<(int)((long)Bb_ * Nn_ * 64 / 256), 256, 0, stream>>>(Opart, lbuf, refsT);

    // 5. catT[:, :256] = qryTb + refsT @ Wproj^T + bproj
    gemm64<<<dim3(C / 64, Nn_ / 64, Bb_), 256, 0, stream>>>(
        refsT, Wprojb, nullptr, catT, Nn_, C, C, C, C, 2 * C,
        MN, 0, (long)Nn_ * 2 * C,
        nullptr, bproj, 0, nullptr, qryTb, C, MN, 1.0f, 0);

    // 6. catT[:, 256:] = fused cross attention (LN2 folded)
    cross_fused<<<Bb_ * (Nn_ / 64), 256, 0, stream>>>(
        qryTb, meanb, invb, ktg, sgbp, vtil, bout, catT);

    // 7. implicit conv3x3 (tap-adjacent dispatch) + fused reduce(relu)
    conv3x3_gemm<<<dim3(2 * 9, 32, Bb_), 256, 0, stream>>>(catT, Wtap, convPart);
    reduce_partials<<<(int)((long)Bb_ * MN / 1024), 256, 0, stream>>>(
        convPart, 9 * MN, MN, y1T, MN);

    // 8. out = qry + Wf2 @ y1 + bf2   (fp32 [B][C][N])
    gemm64<<<dim3(Nn_ / 64, C / 64, Bb_), 256, 0, stream>>>(
        Wf2b, y1T, out, nullptr, C, Nn_, C, C, C, Nn_,
        0, MN, CN,
        bf2, nullptr, 0, qry, nullptr, Nn_, CN, 1.0f, 0);
}